// Round 8
// baseline (3948.083 us; speedup 1.0000x reference)
//
#include <hip/hip_runtime.h>
#include <math.h>

#define NPTS 4096
#define FD   128
#define NITER 200
#define INVN (1.0f / 4096.0f)
#define NBLK 256
#define NGRP 16
#define GRPSZ (NBLK / NGRP)
#define SMEM_BYTES (NPTS * 4)            // 16 KB swizzled xs

typedef unsigned int uint32;
typedef unsigned long long ull;

__device__ __forceinline__ float sigmoidf_(float x) { return 1.0f / (1.0f + expf(-x)); }

__device__ __forceinline__ unsigned short f2bf(float f) {
    uint32 x = __float_as_uint(f);
    uint32 r = x + 0x7fffu + ((x >> 16) & 1u);   // RNE; inputs are positive finite
    return (unsigned short)(r >> 16);
}

// float4-group swizzle for xs (16-B granularity)
__device__ __forceinline__ int sgrp(int G) { return G ^ ((G >> 3) & 7); }

// ---- hierarchical grid barrier: arrival 16 groups, chained release ----
// bar[0] = root (gen<<8 | count); bar[64*(1+g)] = group g (gen<<8 | count); 256 B apart
__device__ __forceinline__ void gbar(unsigned* bar, int tid, int bid) {
    asm volatile("s_waitcnt vmcnt(0)" ::: "memory");   // u/v stores committed
    __syncthreads();
    if (tid == 0) {
        unsigned* grp = bar + 64 * (1 + (bid >> 4));
        unsigned old = __hip_atomic_fetch_add(grp, 1u, __ATOMIC_RELAXED, __HIP_MEMORY_SCOPE_AGENT);
        unsigned gen = old >> 8;
        if ((old & 0xFFu) == (unsigned)(GRPSZ - 1)) {
            // last in group -> arrive at root
            unsigned rold = __hip_atomic_fetch_add(bar, 1u, __ATOMIC_RELAXED, __HIP_MEMORY_SCOPE_AGENT);
            unsigned rgen = rold >> 8;
            if ((rold & 0xFFu) == (unsigned)(NGRP - 1)) {
                __hip_atomic_fetch_add(bar, (1u << 8) - (unsigned)NGRP,
                                       __ATOMIC_RELAXED, __HIP_MEMORY_SCOPE_AGENT);
            } else {
                int gd = 0;
                while ((__hip_atomic_load(bar, __ATOMIC_RELAXED, __HIP_MEMORY_SCOPE_AGENT) >> 8) == rgen) {
                    __builtin_amdgcn_s_sleep(1);
                    if (++gd > (1 << 24)) break;
                }
            }
            // propagate release to my group: bump gen, reset count
            __hip_atomic_fetch_add(grp, (1u << 8) - (unsigned)GRPSZ,
                                   __ATOMIC_RELAXED, __HIP_MEMORY_SCOPE_AGENT);
        } else {
            int gd = 0;
            while ((__hip_atomic_load(grp, __ATOMIC_RELAXED, __HIP_MEMORY_SCOPE_AGENT) >> 8) == gen) {
                __builtin_amdgcn_s_sleep(1);
                if (++gd > (1 << 24)) break;
            }
        }
    }
    __syncthreads();
}

// dot of 16 bf16 (2 uint4) with 16 fp32
__device__ __forceinline__ float dot16(uint4 a, uint4 b, const float* uu) {
    float acc = 0.0f;
    uint32 kw[8] = {a.x, a.y, a.z, a.w, b.x, b.y, b.z, b.w};
    #pragma unroll
    for (int q = 0; q < 8; ++q)
        acc += __uint_as_float(kw[q] << 16)          * uu[2*q]
             + __uint_as_float(kw[q] & 0xffff0000u)  * uu[2*q+1];
    return acc;
}

// helpers for the non-cooperative fallback path
__device__ __forceinline__ float wave_red_sum(float a) {
    #pragma unroll
    for (int m = 32; m >= 1; m >>= 1) a += __shfl_xor(a, m, 64);
    return a;
}

__device__ __forceinline__ float bf16_row_dot(const unsigned short* __restrict__ Krow,
                                              const float* __restrict__ x,
                                              int lane, int first)
{
    const float4* kp = (const float4*)Krow;
    const float4* xp = (const float4*)x;
    float acc = 0.0f;
    #pragma unroll
    for (int s = 0; s < 8; ++s) {
        int i = s*64 + lane;
        float4 kk = kp[i];
        const uint32* kw = (const uint32*)&kk;
        float xx[8];
        if (first) {
            #pragma unroll
            for (int q = 0; q < 8; ++q) xx[q] = 1.0f;
        } else {
            float4 x0 = xp[i*2], x1 = xp[i*2 + 1];
            xx[0]=x0.x; xx[1]=x0.y; xx[2]=x0.z; xx[3]=x0.w;
            xx[4]=x1.x; xx[5]=x1.y; xx[6]=x1.z; xx[7]=x1.w;
        }
        #pragma unroll
        for (int q = 0; q < 4; ++q) {
            acc += __uint_as_float(kw[q] << 16)         * xx[2*q]
                 + __uint_as_float(kw[q] & 0xffff0000u) * xx[2*q+1];
        }
    }
    return acc;
}

__device__ __forceinline__ float f32_row_dot(const float* __restrict__ Krow,
                                             const float* __restrict__ x, int lane)
{
    const float4* kp = (const float4*)Krow;
    const float4* xp = (const float4*)x;
    float acc = 0.0f;
    #pragma unroll
    for (int s = 0; s < 16; ++s) {
        int i = s*64 + lane;
        float4 kk = kp[i], xx = xp[i];
        acc += kk.x*xx.x + kk.y*xx.y + kk.z*xx.z + kk.w*xx.w;
    }
    return acc;
}

__device__ __forceinline__ float f32_col_dot(const float* __restrict__ K,
                                             const float* __restrict__ u,
                                             int col, int lane, int first)
{
    float acc = 0.0f;
    for (int i = lane; i < NPTS; i += 64)
        acc += K[(size_t)i*NPTS + col] * (first ? 1.0f : u[i]);
    return acc;
}

// ---------------- feature MLP kernel: one block (128 thr) per row, side = blockIdx.y ----------------
__global__ void feat_kernel(const float* __restrict__ sn2d, const float* __restrict__ sn3d,
                            const float* __restrict__ pix2d, const float* __restrict__ pts3d,
                            const float* __restrict__ intr,
                            const float* __restrict__ W1i, const float* __restrict__ b1i,
                            const float* __restrict__ W2i, const float* __restrict__ b2i,
                            const float* __restrict__ W3i, const float* __restrict__ b3i,
                            const float* __restrict__ W1p, const float* __restrict__ b1p,
                            const float* __restrict__ W2p, const float* __restrict__ b2p,
                            const float* __restrict__ W3p, const float* __restrict__ b3p,
                            float* __restrict__ f2d, float* __restrict__ f3d,
                            float* __restrict__ x2, float* __restrict__ y2)
{
    const int row  = blockIdx.x;
    const int side = blockIdx.y;
    const int tid  = threadIdx.x;

    __shared__ float xin[6];
    __shared__ float h1s[64];
    __shared__ float h2s[128];
    __shared__ float red[2];

    const float* W1 = side ? W1p : W1i;  const float* B1 = side ? b1p : b1i;
    const float* W2 = side ? W2p : W2i;  const float* B2 = side ? b2p : b2i;
    const float* W3 = side ? W3p : W3i;  const float* B3 = side ? b3p : b3i;

    if (tid == 0) {
        if (side == 0) {
            float a0 = sn2d[row*3+0], a1 = sn2d[row*3+1], a2 = sn2d[row*3+2];
            float n = fmaxf(sqrtf(a0*a0 + a1*a1 + a2*a2), 1e-12f);
            xin[0] = a0/n; xin[1] = a1/n; xin[2] = a2/n;
            float m00 = intr[0], m01 = intr[1], m02 = intr[2];
            float m10 = intr[3], m11 = intr[4], m12 = intr[5];
            float m20 = intr[6], m21 = intr[7], m22 = intr[8];
            float det = m00*(m11*m22 - m12*m21) - m01*(m10*m22 - m12*m20) + m02*(m10*m21 - m11*m20);
            float id = 1.0f/det;
            float i00 = (m11*m22 - m12*m21)*id;
            float i01 = (m02*m21 - m01*m22)*id;
            float i02 = (m01*m12 - m02*m11)*id;
            float i10 = (m12*m20 - m10*m22)*id;
            float i11 = (m00*m22 - m02*m20)*id;
            float i12 = (m02*m10 - m00*m12)*id;
            float i20 = (m10*m21 - m11*m20)*id;
            float i21 = (m01*m20 - m00*m21)*id;
            float i22 = (m00*m11 - m01*m10)*id;
            float px = pix2d[row*2+0], py = pix2d[row*2+1];
            float e0 = i00*px + i01*py + i02;
            float e1 = i10*px + i11*py + i12;
            float e2 = i20*px + i21*py + i22;
            float nb = fmaxf(sqrtf(e0*e0 + e1*e1 + e2*e2), 1e-12f);
            xin[3] = e1/nb; xin[4] = e0/nb; xin[5] = e2/nb;
        } else {
            float a0 = sn3d[row*3+0], a1 = sn3d[row*3+1], a2 = sn3d[row*3+2];
            float n = fmaxf(sqrtf(a0*a0 + a1*a1 + a2*a2), 1e-12f);
            xin[0] = a0/n; xin[1] = a1/n; xin[2] = a2/n;
            float p0 = pts3d[row*3+0], p1 = pts3d[row*3+1], p2 = pts3d[row*3+2];
            float pn = fmaxf(sqrtf(p0*p0 + p1*p1 + p2*p2), 1e-12f);
            xin[3] = p0/pn; xin[4] = p1/pn; xin[5] = p2/pn;
        }
    }
    __syncthreads();
    if (tid < 64) {
        float a = B1[tid];
        #pragma unroll
        for (int k = 0; k < 6; ++k) a += xin[k] * W1[tid*6 + k];
        h1s[tid] = sigmoidf_(a);
    }
    __syncthreads();
    {
        float a = B2[tid];
        #pragma unroll 8
        for (int k = 0; k < 64; ++k) a += h1s[k] * W2[tid*64 + k];
        h2s[tid] = sigmoidf_(a);
    }
    __syncthreads();
    float a = B3[tid];
    #pragma unroll 8
    for (int k = 0; k < 128; ++k) a += h2s[k] * W3[tid*128 + k];
    float o = sigmoidf_(a);

    float ss = o*o;
    #pragma unroll
    for (int m = 32; m >= 1; m >>= 1) ss += __shfl_xor(ss, m, 64);
    if ((tid & 63) == 0) red[tid >> 6] = ss;
    __syncthreads();
    float tot = red[0] + red[1];
    float n = fmaxf(sqrtf(tot), 1e-12f);
    float f = o / n;
    (side ? f3d : f2d)[row*FD + tid] = f;

    float ss2 = f*f;
    #pragma unroll
    for (int m = 32; m >= 1; m >>= 1) ss2 += __shfl_xor(ss2, m, 64);
    __syncthreads();
    if ((tid & 63) == 0) red[tid >> 6] = ss2;
    __syncthreads();
    if (tid == 0) (side ? y2 : x2)[row] = red[0] + red[1];
}

// ---------------- cost kernel: 64x64 tile; writes fp32 K, bf16 Kb (row), bf16 KbT (col), inits barrier ----------------
__global__ void __launch_bounds__(256) cost_kernel(const float* __restrict__ f2d, const float* __restrict__ f3d,
                                                   const float* __restrict__ x2, const float* __restrict__ y2,
                                                   float* __restrict__ K,
                                                   unsigned short* __restrict__ Kb,
                                                   unsigned short* __restrict__ KbT,
                                                   unsigned* __restrict__ bar,
                                                   int wantB, int wantT)
{
    __shared__ float As[128][64];
    __shared__ float Bs[128][64];
    const int tid = threadIdx.x;
    const int i0 = blockIdx.y * 64;
    const int j0 = blockIdx.x * 64;

    if (bar && blockIdx.x == 0 && blockIdx.y == 0 && tid < 1 + NGRP)
        __hip_atomic_store(&bar[tid * 64], 0u, __ATOMIC_RELAXED, __HIP_MEMORY_SCOPE_AGENT);

    {
        int r0 = tid >> 5;
        int c  = (tid & 31) * 4;
        for (int rr = r0; rr < 64; rr += 8) {
            float4 av = *(const float4*)(f2d + (size_t)(i0+rr)*FD + c);
            As[c+0][rr] = av.x; As[c+1][rr] = av.y; As[c+2][rr] = av.z; As[c+3][rr] = av.w;
            float4 bv = *(const float4*)(f3d + (size_t)(j0+rr)*FD + c);
            Bs[c+0][rr] = bv.x; Bs[c+1][rr] = bv.y; Bs[c+2][rr] = bv.z; Bs[c+3][rr] = bv.w;
        }
    }
    __syncthreads();

    const int tx = tid & 15;
    const int ty = tid >> 4;
    float acc[4][4] = {};
    for (int k = 0; k < 128; ++k) {
        float4 av = *(const float4*)&As[k][ty*4];
        float4 bv = *(const float4*)&Bs[k][tx*4];
        float aa[4] = {av.x, av.y, av.z, av.w};
        float bb[4] = {bv.x, bv.y, bv.z, bv.w};
        #pragma unroll
        for (int i = 0; i < 4; ++i)
            #pragma unroll
            for (int j = 0; j < 4; ++j)
                acc[i][j] += aa[i] * bb[j];
    }

    float kv[4][4];
    #pragma unroll
    for (int i = 0; i < 4; ++i) {
        int gi = i0 + ty*4 + i;
        float xv = x2[gi];
        #pragma unroll
        for (int j = 0; j < 4; ++j) {
            int gj = j0 + tx*4 + j;
            float d2 = xv + y2[gj] - 2.0f * acc[i][j];
            d2 = fmaxf(d2, 1e-12f);
            kv[i][j] = expf(-sqrtf(d2) * 10.0f);
        }
    }

    #pragma unroll
    for (int i = 0; i < 4; ++i) {
        int gi = i0 + ty*4 + i;
        *(float4*)(K + (size_t)gi*NPTS + j0 + tx*4) = make_float4(kv[i][0], kv[i][1], kv[i][2], kv[i][3]);
        if (wantB) {
            uint32 lo = (uint32)f2bf(kv[i][0]) | ((uint32)f2bf(kv[i][1]) << 16);
            uint32 hi = (uint32)f2bf(kv[i][2]) | ((uint32)f2bf(kv[i][3]) << 16);
            uint2 p; p.x = lo; p.y = hi;
            *(uint2*)(Kb + (size_t)gi*NPTS + j0 + tx*4) = p;
        }
    }
    if (wantT) {
        #pragma unroll
        for (int j = 0; j < 4; ++j) {
            int gj = j0 + tx*4 + j;
            uint32 lo = (uint32)f2bf(kv[0][j]) | ((uint32)f2bf(kv[1][j]) << 16);
            uint32 hi = (uint32)f2bf(kv[2][j]) | ((uint32)f2bf(kv[3][j]) << 16);
            uint2 p; p.x = lo; p.y = hi;
            *(uint2*)(KbT + (size_t)gj*NPTS + i0 + ty*4) = p;
        }
    }
}

// ---------------- persistent cooperative Sinkhorn v5: BOTH K slices in registers ----------------
// wave w = (g = w>>2 row/col group, s = w&3 slice). Lane l owns elements [s*1024+16l, +16).
// amdgpu_waves_per_eu(4,4): pin EXACTLY 4 waves/EU (1 block/CU) -> 128-VGPR budget,
// so the 64-VGPR kq+kt tile stays in registers (round-7 failure: compiler kept 64 and remat'd).
__global__ void __launch_bounds__(1024)
__attribute__((amdgpu_waves_per_eu(4, 4)))
sinkhorn_kernel(float* __restrict__ K,
                const unsigned short* __restrict__ Kb,
                const unsigned short* __restrict__ KbT,
                float* __restrict__ u,
                float* __restrict__ v,
                unsigned* __restrict__ bar)
{
    extern __shared__ char smem[];
    float* xs = (float*)smem;            // 16 KB swizzled u-or-v vector
    __shared__ float red[16][4];
    __shared__ float us[16];

    const int tid  = threadIdx.x;
    const int w    = tid >> 6;
    const int lane = tid & 63;
    const int g    = w >> 2;
    const int s    = w & 3;
    const int bid  = blockIdx.x;
    const int base = bid * 16;

    // one-time: my 4 rows x 1024-elem slice of BOTH Kb and KbT into registers (64 VGPRs)
    uint4 kq[4][2], kt[4][2];
    #pragma unroll
    for (int j = 0; j < 4; ++j) {
        const size_t off = (size_t)(base + 4*g + j) * NPTS + s*1024 + lane*16;
        const uint4* kp = (const uint4*)(Kb  + off);
        const uint4* tp = (const uint4*)(KbT + off);
        kq[j][0] = kp[0]; kq[j][1] = kp[1];
        kt[j][0] = tp[0]; kt[j][1] = tp[1];
    }

    for (int it = 0; it <= NITER; ++it) {
        // ---- stage u (or ones) into swizzled xs: thread t owns float4-group t ----
        if (it == 0) {
            *(float4*)((char*)xs + 16*sgrp(tid)) = make_float4(1.f, 1.f, 1.f, 1.f);
        } else {
            const ull* gp = (const ull*)u;
            ull a = __hip_atomic_load(&gp[2*tid],   __ATOMIC_RELAXED, __HIP_MEMORY_SCOPE_AGENT);
            ull b = __hip_atomic_load(&gp[2*tid+1], __ATOMIC_RELAXED, __HIP_MEMORY_SCOPE_AGENT);
            ull* dst = (ull*)((char*)xs + 16*sgrp(tid));
            dst[0] = a; dst[1] = b;
        }
        __syncthreads();

        // ---- half A: v_c = c / dot(K[:,c], u), cols 4g..4g+3 slice s from kt registers ----
        {
            float uu[16];
            #pragma unroll
            for (int k = 0; k < 4; ++k) {
                int G = s*256 + lane*4 + k;
                *(float4*)&uu[4*k] = *(const float4*)((const char*)xs + 16*sgrp(G));
            }
            float p[4];
            #pragma unroll
            for (int j = 0; j < 4; ++j) p[j] = dot16(kt[j][0], kt[j][1], uu);

            #pragma unroll
            for (int j = 0; j < 4; ++j)
                #pragma unroll
                for (int m = 32; m >= 1; m >>= 1) p[j] += __shfl_xor(p[j], m, 64);
            if (lane == 0) {
                red[4*g+0][s] = p[0]; red[4*g+1][s] = p[1];
                red[4*g+2][s] = p[2]; red[4*g+3][s] = p[3];
            }
            __syncthreads();
            if (tid < 16) {
                float4 rr = *(float4*)&red[tid][0];
                float val = INVN / (rr.x + rr.y + rr.z + rr.w);
                __hip_atomic_store(&v[base + tid], val, __ATOMIC_RELAXED, __HIP_MEMORY_SCOPE_AGENT);
            }
        }
        gbar(bar, tid, bid);
        if (it == NITER) break;

        // ---- stage v into swizzled xs ----
        {
            const ull* gp = (const ull*)v;
            ull a = __hip_atomic_load(&gp[2*tid],   __ATOMIC_RELAXED, __HIP_MEMORY_SCOPE_AGENT);
            ull b = __hip_atomic_load(&gp[2*tid+1], __ATOMIC_RELAXED, __HIP_MEMORY_SCOPE_AGENT);
            ull* dst = (ull*)((char*)xs + 16*sgrp(tid));
            dst[0] = a; dst[1] = b;
        }
        __syncthreads();

        // ---- half B: u_r = r / dot(K[r,:], v), rows 4g..4g+3 slice s from kq registers ----
        {
            float uu[16];
            #pragma unroll
            for (int k = 0; k < 4; ++k) {
                int G = s*256 + lane*4 + k;
                *(float4*)&uu[4*k] = *(const float4*)((const char*)xs + 16*sgrp(G));
            }
            float p[4];
            #pragma unroll
            for (int j = 0; j < 4; ++j) p[j] = dot16(kq[j][0], kq[j][1], uu);

            #pragma unroll
            for (int j = 0; j < 4; ++j)
                #pragma unroll
                for (int m = 32; m >= 1; m >>= 1) p[j] += __shfl_xor(p[j], m, 64);
            if (lane == 0) {
                red[4*g+0][s] = p[0]; red[4*g+1][s] = p[1];
                red[4*g+2][s] = p[2]; red[4*g+3][s] = p[3];
            }
            __syncthreads();
            if (tid < 16) {
                float4 rr = *(float4*)&red[tid][0];
                float val = INVN / (rr.x + rr.y + rr.z + rr.w);
                us[tid] = val;
                __hip_atomic_store(&u[base + tid], val, __ATOMIC_RELAXED, __HIP_MEMORY_SCOPE_AGENT);
            }
        }
        gbar(bar, tid, bid);
    }

    // ---- final: P = u[:,None] * K * v[None,:] in place over d_out (fp32 K, exact) ----
    {
        const ull* gp = (const ull*)v;
        ull a = __hip_atomic_load(&gp[2*tid],   __ATOMIC_RELAXED, __HIP_MEMORY_SCOPE_AGENT);
        ull b = __hip_atomic_load(&gp[2*tid+1], __ATOMIC_RELAXED, __HIP_MEMORY_SCOPE_AGENT);
        ull* dst = (ull*)((char*)xs + 16*sgrp(tid));
        dst[0] = a; dst[1] = b;
        __syncthreads();

        const float ur = us[w];                      // wave w scales row base+w
        float4* kp = (float4*)(K + (size_t)(base + w) * NPTS);
        #pragma unroll
        for (int t = 0; t < 16; ++t) {
            int G = t*64 + lane;
            float4 kk = kp[G];
            float4 vv = *(const float4*)((const char*)xs + 16*sgrp(G));
            kk.x *= ur * vv.x; kk.y *= ur * vv.y; kk.z *= ur * vv.z; kk.w *= ur * vv.w;
            kp[G] = kk;
        }
    }
}

// ---------------- non-cooperative fallback kernels (used only if coop launch fails) ----------------
__global__ void __launch_bounds__(1024) stepA_kernel(const float* __restrict__ K,
                                                     const unsigned short* __restrict__ KbT,
                                                     const float* __restrict__ u, float* __restrict__ v,
                                                     int first, int modeA)
{
    const int w = threadIdx.x >> 6, lane = threadIdx.x & 63;
    const int r = blockIdx.x * 16 + w;
    float acc = modeA ? bf16_row_dot(KbT + (size_t)r * NPTS, u, lane, first)
                      : f32_col_dot(K, u, r, lane, first);
    acc = wave_red_sum(acc);
    if (lane == 0) v[r] = INVN / acc;
}

__global__ void __launch_bounds__(1024) stepB_kernel(const float* __restrict__ K,
                                                     const unsigned short* __restrict__ Kb,
                                                     const float* __restrict__ v, float* __restrict__ u,
                                                     int modeB)
{
    const int w = threadIdx.x >> 6, lane = threadIdx.x & 63;
    const int r = blockIdx.x * 16 + w;
    float acc = modeB ? bf16_row_dot(Kb + (size_t)r * NPTS, v, lane, 0)
                      : f32_row_dot(K + (size_t)r * NPTS, v, lane);
    acc = wave_red_sum(acc);
    if (lane == 0) u[r] = INVN / acc;
}

__global__ void __launch_bounds__(1024) final_kernel(float* __restrict__ K,
                                                     const float* __restrict__ u,
                                                     const float* __restrict__ v)
{
    const int w = threadIdx.x >> 6, lane = threadIdx.x & 63;
    const int r = blockIdx.x * 16 + w;
    const float ur = u[r];
    float4* kp = (float4*)(K + (size_t)r * NPTS);
    const float4* vp = (const float4*)v;
    #pragma unroll
    for (int s = 0; s < 16; ++s) {
        int e4 = s * 64 + lane;
        float4 kk = kp[e4], vv = vp[e4];
        kk.x *= ur * vv.x; kk.y *= ur * vv.y; kk.z *= ur * vv.z; kk.w *= ur * vv.w;
        kp[e4] = kk;
    }
}

extern "C" void kernel_launch(void* const* d_in, const int* in_sizes, int n_in,
                              void* d_out, int out_size, void* d_ws, size_t ws_size,
                              hipStream_t stream)
{
    (void)in_sizes; (void)n_in; (void)out_size;
    const float* sn2d  = (const float*)d_in[0];
    const float* sn3d  = (const float*)d_in[1];
    const float* pix2d = (const float*)d_in[2];
    const float* pts3d = (const float*)d_in[3];
    const float* intr  = (const float*)d_in[4];
    const float* W1i = (const float*)d_in[5];  const float* b1i = (const float*)d_in[6];
    const float* W2i = (const float*)d_in[7];  const float* b2i = (const float*)d_in[8];
    const float* W3i = (const float*)d_in[9];  const float* b3i = (const float*)d_in[10];
    const float* W1p = (const float*)d_in[11]; const float* b1p = (const float*)d_in[12];
    const float* W2p = (const float*)d_in[13]; const float* b2p = (const float*)d_in[14];
    const float* W3p = (const float*)d_in[15]; const float* b3p = (const float*)d_in[16];

    float* ws  = (float*)d_ws;
    float* f2d = ws;                       // 4096*128
    float* f3d = f2d + NPTS*FD;            // 4096*128
    float* x2  = f3d + NPTS*FD;            // 4096
    float* y2  = x2 + NPTS;                // 4096
    float* u   = y2 + NPTS;                // 4096
    float* v   = u  + NPTS;                // 4096
    unsigned short* KbT = (unsigned short*)(v + NPTS);   // 33.55 MB
    unsigned short* Kb  = KbT + (size_t)NPTS*NPTS;       // 33.55 MB
    unsigned* bar = (unsigned*)(Kb + (size_t)NPTS*NPTS); // root + 16 group words, 256 B apart
    float* K   = (float*)d_out;            // fp32 K, scaled in place to P at the end

    const size_t base_bytes = (size_t)(2*NPTS*FD + 4*NPTS) * 4;
    const size_t bf16_bytes = (size_t)NPTS * NPTS * 2;
    const size_t need_full  = base_bytes + 2*bf16_bytes + 8192;
    int coop_ok = (ws_size >= need_full) ? 1 : 0;
    int modeA = (ws_size >= base_bytes + bf16_bytes)   ? 1 : 0;
    int modeB = (ws_size >= base_bytes + 2*bf16_bytes) ? 1 : 0;

    feat_kernel<<<dim3(NPTS, 2), 128, 0, stream>>>(sn2d, sn3d, pix2d, pts3d, intr,
        W1i, b1i, W2i, b2i, W3i, b3i, W1p, b1p, W2p, b2p, W3p, b3p,
        f2d, f3d, x2, y2);

    cost_kernel<<<dim3(64, 64), 256, 0, stream>>>(f2d, f3d, x2, y2, K, Kb, KbT,
                                                  coop_ok ? bar : (unsigned*)0,
                                                  modeB, modeA);

    hipError_t err = hipErrorUnknown;
    if (coop_ok) {
        void* args[] = { (void*)&K, (void*)&Kb, (void*)&KbT, (void*)&u, (void*)&v, (void*)&bar };
        err = hipLaunchCooperativeKernel((const void*)sinkhorn_kernel,
                                         dim3(NBLK), dim3(1024), args, SMEM_BYTES, stream);
    }
    if (err != hipSuccess) {
        // non-cooperative fallback: same math, one launch per half-step
        stepA_kernel<<<256, 1024, 0, stream>>>(K, KbT, u, v, 1, modeA);
        for (int i = 0; i < NITER; ++i) {
            stepB_kernel<<<256, 1024, 0, stream>>>(K, Kb, v, u, modeB);
            stepA_kernel<<<256, 1024, 0, stream>>>(K, KbT, u, v, 0, modeA);
        }
        final_kernel<<<256, 1024, 0, stream>>>(K, u, v);
    }
}

// Round 9
// 2451.491 us; speedup vs baseline: 1.6105x; 1.6105x over previous
//
#include <hip/hip_runtime.h>
#include <math.h>

#define NPTS 4096
#define FD   128
#define NITER 200
#define INVN (1.0f / 4096.0f)
#define NBLK 256
#define NGRP 16
#define GRPSZ (NBLK / NGRP)
#define SMEM_BYTES (NPTS * 4)            // 16 KB swizzled xs

typedef unsigned int uint32;
typedef unsigned long long ull;
typedef unsigned int u32x4 __attribute__((ext_vector_type(4)));

__device__ __forceinline__ float sigmoidf_(float x) { return 1.0f / (1.0f + expf(-x)); }

__device__ __forceinline__ unsigned short f2bf(float f) {
    uint32 x = __float_as_uint(f);
    uint32 r = x + 0x7fffu + ((x >> 16) & 1u);   // RNE; inputs are positive finite
    return (unsigned short)(r >> 16);
}

// float4-group swizzle for xs (16-B granularity)
__device__ __forceinline__ int sgrp(int G) { return G ^ ((G >> 3) & 7); }

// ---- hierarchical grid barrier: arrival 16 groups, chained release ----
// bar[0] = root (gen<<8 | count); bar[64*(1+g)] = group g (gen<<8 | count); 256 B apart
__device__ __forceinline__ void gbar(unsigned* bar, int tid, int bid) {
    asm volatile("s_waitcnt vmcnt(0)" ::: "memory");   // u/v stores committed
    __syncthreads();
    if (tid == 0) {
        unsigned* grp = bar + 64 * (1 + (bid >> 4));
        unsigned old = __hip_atomic_fetch_add(grp, 1u, __ATOMIC_RELAXED, __HIP_MEMORY_SCOPE_AGENT);
        unsigned gen = old >> 8;
        if ((old & 0xFFu) == (unsigned)(GRPSZ - 1)) {
            // last in group -> arrive at root
            unsigned rold = __hip_atomic_fetch_add(bar, 1u, __ATOMIC_RELAXED, __HIP_MEMORY_SCOPE_AGENT);
            unsigned rgen = rold >> 8;
            if ((rold & 0xFFu) == (unsigned)(NGRP - 1)) {
                __hip_atomic_fetch_add(bar, (1u << 8) - (unsigned)NGRP,
                                       __ATOMIC_RELAXED, __HIP_MEMORY_SCOPE_AGENT);
            } else {
                int gd = 0;
                while ((__hip_atomic_load(bar, __ATOMIC_RELAXED, __HIP_MEMORY_SCOPE_AGENT) >> 8) == rgen) {
                    __builtin_amdgcn_s_sleep(1);
                    if (++gd > (1 << 24)) break;
                }
            }
            // propagate release to my group: bump gen, reset count
            __hip_atomic_fetch_add(grp, (1u << 8) - (unsigned)GRPSZ,
                                   __ATOMIC_RELAXED, __HIP_MEMORY_SCOPE_AGENT);
        } else {
            int gd = 0;
            while ((__hip_atomic_load(grp, __ATOMIC_RELAXED, __HIP_MEMORY_SCOPE_AGENT) >> 8) == gen) {
                __builtin_amdgcn_s_sleep(1);
                if (++gd > (1 << 24)) break;
            }
        }
    }
    __syncthreads();
}

// dot of 16 bf16 (2 u32x4) with 16 fp32
__device__ __forceinline__ float dot16(u32x4 a, u32x4 b, const float* uu) {
    float acc = 0.0f;
    #pragma unroll
    for (int q = 0; q < 4; ++q)
        acc += __uint_as_float(a[q] << 16)          * uu[2*q]
             + __uint_as_float(a[q] & 0xffff0000u)  * uu[2*q+1];
    #pragma unroll
    for (int q = 0; q < 4; ++q)
        acc += __uint_as_float(b[q] << 16)          * uu[8 + 2*q]
             + __uint_as_float(b[q] & 0xffff0000u)  * uu[8 + 2*q+1];
    return acc;
}

// helpers for the non-cooperative fallback path
__device__ __forceinline__ float wave_red_sum(float a) {
    #pragma unroll
    for (int m = 32; m >= 1; m >>= 1) a += __shfl_xor(a, m, 64);
    return a;
}

__device__ __forceinline__ float bf16_row_dot(const unsigned short* __restrict__ Krow,
                                              const float* __restrict__ x,
                                              int lane, int first)
{
    const float4* kp = (const float4*)Krow;
    const float4* xp = (const float4*)x;
    float acc = 0.0f;
    #pragma unroll
    for (int s = 0; s < 8; ++s) {
        int i = s*64 + lane;
        float4 kk = kp[i];
        const uint32* kw = (const uint32*)&kk;
        float xx[8];
        if (first) {
            #pragma unroll
            for (int q = 0; q < 8; ++q) xx[q] = 1.0f;
        } else {
            float4 x0 = xp[i*2], x1 = xp[i*2 + 1];
            xx[0]=x0.x; xx[1]=x0.y; xx[2]=x0.z; xx[3]=x0.w;
            xx[4]=x1.x; xx[5]=x1.y; xx[6]=x1.z; xx[7]=x1.w;
        }
        #pragma unroll
        for (int q = 0; q < 4; ++q) {
            acc += __uint_as_float(kw[q] << 16)         * xx[2*q]
                 + __uint_as_float(kw[q] & 0xffff0000u) * xx[2*q+1];
        }
    }
    return acc;
}

__device__ __forceinline__ float f32_row_dot(const float* __restrict__ Krow,
                                             const float* __restrict__ x, int lane)
{
    const float4* kp = (const float4*)Krow;
    const float4* xp = (const float4*)x;
    float acc = 0.0f;
    #pragma unroll
    for (int s = 0; s < 16; ++s) {
        int i = s*64 + lane;
        float4 kk = kp[i], xx = xp[i];
        acc += kk.x*xx.x + kk.y*xx.y + kk.z*xx.z + kk.w*xx.w;
    }
    return acc;
}

__device__ __forceinline__ float f32_col_dot(const float* __restrict__ K,
                                             const float* __restrict__ u,
                                             int col, int lane, int first)
{
    float acc = 0.0f;
    for (int i = lane; i < NPTS; i += 64)
        acc += K[(size_t)i*NPTS + col] * (first ? 1.0f : u[i]);
    return acc;
}

// ---------------- feature MLP kernel: one block (128 thr) per row, side = blockIdx.y ----------------
__global__ void feat_kernel(const float* __restrict__ sn2d, const float* __restrict__ sn3d,
                            const float* __restrict__ pix2d, const float* __restrict__ pts3d,
                            const float* __restrict__ intr,
                            const float* __restrict__ W1i, const float* __restrict__ b1i,
                            const float* __restrict__ W2i, const float* __restrict__ b2i,
                            const float* __restrict__ W3i, const float* __restrict__ b3i,
                            const float* __restrict__ W1p, const float* __restrict__ b1p,
                            const float* __restrict__ W2p, const float* __restrict__ b2p,
                            const float* __restrict__ W3p, const float* __restrict__ b3p,
                            float* __restrict__ f2d, float* __restrict__ f3d,
                            float* __restrict__ x2, float* __restrict__ y2)
{
    const int row  = blockIdx.x;
    const int side = blockIdx.y;
    const int tid  = threadIdx.x;

    __shared__ float xin[6];
    __shared__ float h1s[64];
    __shared__ float h2s[128];
    __shared__ float red[2];

    const float* W1 = side ? W1p : W1i;  const float* B1 = side ? b1p : b1i;
    const float* W2 = side ? W2p : W2i;  const float* B2 = side ? b2p : b2i;
    const float* W3 = side ? W3p : W3i;  const float* B3 = side ? b3p : b3i;

    if (tid == 0) {
        if (side == 0) {
            float a0 = sn2d[row*3+0], a1 = sn2d[row*3+1], a2 = sn2d[row*3+2];
            float n = fmaxf(sqrtf(a0*a0 + a1*a1 + a2*a2), 1e-12f);
            xin[0] = a0/n; xin[1] = a1/n; xin[2] = a2/n;
            float m00 = intr[0], m01 = intr[1], m02 = intr[2];
            float m10 = intr[3], m11 = intr[4], m12 = intr[5];
            float m20 = intr[6], m21 = intr[7], m22 = intr[8];
            float det = m00*(m11*m22 - m12*m21) - m01*(m10*m22 - m12*m20) + m02*(m10*m21 - m11*m20);
            float id = 1.0f/det;
            float i00 = (m11*m22 - m12*m21)*id;
            float i01 = (m02*m21 - m01*m22)*id;
            float i02 = (m01*m12 - m02*m11)*id;
            float i10 = (m12*m20 - m10*m22)*id;
            float i11 = (m00*m22 - m02*m20)*id;
            float i12 = (m02*m10 - m00*m12)*id;
            float i20 = (m10*m21 - m11*m20)*id;
            float i21 = (m01*m20 - m00*m21)*id;
            float i22 = (m00*m11 - m01*m10)*id;
            float px = pix2d[row*2+0], py = pix2d[row*2+1];
            float e0 = i00*px + i01*py + i02;
            float e1 = i10*px + i11*py + i12;
            float e2 = i20*px + i21*py + i22;
            float nb = fmaxf(sqrtf(e0*e0 + e1*e1 + e2*e2), 1e-12f);
            xin[3] = e1/nb; xin[4] = e0/nb; xin[5] = e2/nb;
        } else {
            float a0 = sn3d[row*3+0], a1 = sn3d[row*3+1], a2 = sn3d[row*3+2];
            float n = fmaxf(sqrtf(a0*a0 + a1*a1 + a2*a2), 1e-12f);
            xin[0] = a0/n; xin[1] = a1/n; xin[2] = a2/n;
            float p0 = pts3d[row*3+0], p1 = pts3d[row*3+1], p2 = pts3d[row*3+2];
            float pn = fmaxf(sqrtf(p0*p0 + p1*p1 + p2*p2), 1e-12f);
            xin[3] = p0/pn; xin[4] = p1/pn; xin[5] = p2/pn;
        }
    }
    __syncthreads();
    if (tid < 64) {
        float a = B1[tid];
        #pragma unroll
        for (int k = 0; k < 6; ++k) a += xin[k] * W1[tid*6 + k];
        h1s[tid] = sigmoidf_(a);
    }
    __syncthreads();
    {
        float a = B2[tid];
        #pragma unroll 8
        for (int k = 0; k < 64; ++k) a += h1s[k] * W2[tid*64 + k];
        h2s[tid] = sigmoidf_(a);
    }
    __syncthreads();
    float a = B3[tid];
    #pragma unroll 8
    for (int k = 0; k < 128; ++k) a += h2s[k] * W3[tid*128 + k];
    float o = sigmoidf_(a);

    float ss = o*o;
    #pragma unroll
    for (int m = 32; m >= 1; m >>= 1) ss += __shfl_xor(ss, m, 64);
    if ((tid & 63) == 0) red[tid >> 6] = ss;
    __syncthreads();
    float tot = red[0] + red[1];
    float n = fmaxf(sqrtf(tot), 1e-12f);
    float f = o / n;
    (side ? f3d : f2d)[row*FD + tid] = f;

    float ss2 = f*f;
    #pragma unroll
    for (int m = 32; m >= 1; m >>= 1) ss2 += __shfl_xor(ss2, m, 64);
    __syncthreads();
    if ((tid & 63) == 0) red[tid >> 6] = ss2;
    __syncthreads();
    if (tid == 0) (side ? y2 : x2)[row] = red[0] + red[1];
}

// ---------------- cost kernel: 64x64 tile; writes fp32 K, bf16 Kb (row), bf16 KbT (col), inits barrier ----------------
__global__ void __launch_bounds__(256) cost_kernel(const float* __restrict__ f2d, const float* __restrict__ f3d,
                                                   const float* __restrict__ x2, const float* __restrict__ y2,
                                                   float* __restrict__ K,
                                                   unsigned short* __restrict__ Kb,
                                                   unsigned short* __restrict__ KbT,
                                                   unsigned* __restrict__ bar,
                                                   int wantB, int wantT)
{
    __shared__ float As[128][64];
    __shared__ float Bs[128][64];
    const int tid = threadIdx.x;
    const int i0 = blockIdx.y * 64;
    const int j0 = blockIdx.x * 64;

    if (bar && blockIdx.x == 0 && blockIdx.y == 0 && tid < 1 + NGRP)
        __hip_atomic_store(&bar[tid * 64], 0u, __ATOMIC_RELAXED, __HIP_MEMORY_SCOPE_AGENT);

    {
        int r0 = tid >> 5;
        int c  = (tid & 31) * 4;
        for (int rr = r0; rr < 64; rr += 8) {
            float4 av = *(const float4*)(f2d + (size_t)(i0+rr)*FD + c);
            As[c+0][rr] = av.x; As[c+1][rr] = av.y; As[c+2][rr] = av.z; As[c+3][rr] = av.w;
            float4 bv = *(const float4*)(f3d + (size_t)(j0+rr)*FD + c);
            Bs[c+0][rr] = bv.x; Bs[c+1][rr] = bv.y; Bs[c+2][rr] = bv.z; Bs[c+3][rr] = bv.w;
        }
    }
    __syncthreads();

    const int tx = tid & 15;
    const int ty = tid >> 4;
    float acc[4][4] = {};
    for (int k = 0; k < 128; ++k) {
        float4 av = *(const float4*)&As[k][ty*4];
        float4 bv = *(const float4*)&Bs[k][tx*4];
        float aa[4] = {av.x, av.y, av.z, av.w};
        float bb[4] = {bv.x, bv.y, bv.z, bv.w};
        #pragma unroll
        for (int i = 0; i < 4; ++i)
            #pragma unroll
            for (int j = 0; j < 4; ++j)
                acc[i][j] += aa[i] * bb[j];
    }

    float kv[4][4];
    #pragma unroll
    for (int i = 0; i < 4; ++i) {
        int gi = i0 + ty*4 + i;
        float xv = x2[gi];
        #pragma unroll
        for (int j = 0; j < 4; ++j) {
            int gj = j0 + tx*4 + j;
            float d2 = xv + y2[gj] - 2.0f * acc[i][j];
            d2 = fmaxf(d2, 1e-12f);
            kv[i][j] = expf(-sqrtf(d2) * 10.0f);
        }
    }

    #pragma unroll
    for (int i = 0; i < 4; ++i) {
        int gi = i0 + ty*4 + i;
        *(float4*)(K + (size_t)gi*NPTS + j0 + tx*4) = make_float4(kv[i][0], kv[i][1], kv[i][2], kv[i][3]);
        if (wantB) {
            uint32 lo = (uint32)f2bf(kv[i][0]) | ((uint32)f2bf(kv[i][1]) << 16);
            uint32 hi = (uint32)f2bf(kv[i][2]) | ((uint32)f2bf(kv[i][3]) << 16);
            uint2 p; p.x = lo; p.y = hi;
            *(uint2*)(Kb + (size_t)gi*NPTS + j0 + tx*4) = p;
        }
    }
    if (wantT) {
        #pragma unroll
        for (int j = 0; j < 4; ++j) {
            int gj = j0 + tx*4 + j;
            uint32 lo = (uint32)f2bf(kv[0][j]) | ((uint32)f2bf(kv[1][j]) << 16);
            uint32 hi = (uint32)f2bf(kv[2][j]) | ((uint32)f2bf(kv[3][j]) << 16);
            uint2 p; p.x = lo; p.y = hi;
            *(uint2*)(KbT + (size_t)gj*NPTS + i0 + ty*4) = p;
        }
    }
}

// ---------------- persistent cooperative Sinkhorn v6: K slices pinned in registers ----------------
// wave w = (g = w>>2 row/col group, s = w&3 slice). Lane l owns elements [s*1024+16l, +16).
// amdgpu_waves_per_eu(4,4) -> 128-VGPR budget; the per-iteration asm "+v" pin creates a
// loop-carried register dependence so the compiler CANNOT remat the kq/kt loads (round-8 failure).
__global__ void __launch_bounds__(1024)
__attribute__((amdgpu_waves_per_eu(4, 4)))
sinkhorn_kernel(float* __restrict__ K,
                const unsigned short* __restrict__ Kb,
                const unsigned short* __restrict__ KbT,
                float* __restrict__ u,
                float* __restrict__ v,
                unsigned* __restrict__ bar)
{
    extern __shared__ char smem[];
    float* xs = (float*)smem;            // 16 KB swizzled u-or-v vector
    __shared__ float red[16][4];
    __shared__ float us[16];

    const int tid  = threadIdx.x;
    const int w    = tid >> 6;
    const int lane = tid & 63;
    const int g    = w >> 2;
    const int s    = w & 3;
    const int bid  = blockIdx.x;
    const int base = bid * 16;

    // one-time: my 4 rows x 1024-elem slice of BOTH Kb and KbT into registers (64 VGPRs)
    u32x4 kq[4][2], kt[4][2];
    #pragma unroll
    for (int j = 0; j < 4; ++j) {
        const size_t off = (size_t)(base + 4*g + j) * NPTS + s*1024 + lane*16;
        const u32x4* kp = (const u32x4*)(Kb  + off);
        const u32x4* tp = (const u32x4*)(KbT + off);
        kq[j][0] = kp[0]; kq[j][1] = kp[1];
        kt[j][0] = tp[0]; kt[j][1] = tp[1];
    }

    for (int it = 0; it <= NITER; ++it) {
        // pin the data tile in VGPRs: read-write asm operands form a loop-carried
        // register dependence -> loads cannot be sunk/remat'd into the loop
        #pragma unroll
        for (int j = 0; j < 4; ++j)
            asm volatile("" : "+v"(kq[j][0]), "+v"(kq[j][1]), "+v"(kt[j][0]), "+v"(kt[j][1]));

        // ---- stage u (or ones) into swizzled xs: thread t owns float4-group t ----
        if (it == 0) {
            *(float4*)((char*)xs + 16*sgrp(tid)) = make_float4(1.f, 1.f, 1.f, 1.f);
        } else {
            const ull* gp = (const ull*)u;
            ull a = __hip_atomic_load(&gp[2*tid],   __ATOMIC_RELAXED, __HIP_MEMORY_SCOPE_AGENT);
            ull b = __hip_atomic_load(&gp[2*tid+1], __ATOMIC_RELAXED, __HIP_MEMORY_SCOPE_AGENT);
            ull* dst = (ull*)((char*)xs + 16*sgrp(tid));
            dst[0] = a; dst[1] = b;
        }
        __syncthreads();

        // ---- half A: v_c = c / dot(K[:,c], u), cols 4g..4g+3 slice s from kt registers ----
        {
            float uu[16];
            #pragma unroll
            for (int k = 0; k < 4; ++k) {
                int G = s*256 + lane*4 + k;
                *(float4*)&uu[4*k] = *(const float4*)((const char*)xs + 16*sgrp(G));
            }
            float p[4];
            #pragma unroll
            for (int j = 0; j < 4; ++j) p[j] = dot16(kt[j][0], kt[j][1], uu);

            #pragma unroll
            for (int j = 0; j < 4; ++j)
                #pragma unroll
                for (int m = 32; m >= 1; m >>= 1) p[j] += __shfl_xor(p[j], m, 64);
            if (lane == 0) {
                red[4*g+0][s] = p[0]; red[4*g+1][s] = p[1];
                red[4*g+2][s] = p[2]; red[4*g+3][s] = p[3];
            }
            __syncthreads();
            if (tid < 16) {
                float4 rr = *(float4*)&red[tid][0];
                float val = INVN / (rr.x + rr.y + rr.z + rr.w);
                __hip_atomic_store(&v[base + tid], val, __ATOMIC_RELAXED, __HIP_MEMORY_SCOPE_AGENT);
            }
        }
        gbar(bar, tid, bid);
        if (it == NITER) break;

        // ---- stage v into swizzled xs ----
        {
            const ull* gp = (const ull*)v;
            ull a = __hip_atomic_load(&gp[2*tid],   __ATOMIC_RELAXED, __HIP_MEMORY_SCOPE_AGENT);
            ull b = __hip_atomic_load(&gp[2*tid+1], __ATOMIC_RELAXED, __HIP_MEMORY_SCOPE_AGENT);
            ull* dst = (ull*)((char*)xs + 16*sgrp(tid));
            dst[0] = a; dst[1] = b;
        }
        __syncthreads();

        // ---- half B: u_r = r / dot(K[r,:], v), rows 4g..4g+3 slice s from kq registers ----
        {
            float uu[16];
            #pragma unroll
            for (int k = 0; k < 4; ++k) {
                int G = s*256 + lane*4 + k;
                *(float4*)&uu[4*k] = *(const float4*)((const char*)xs + 16*sgrp(G));
            }
            float p[4];
            #pragma unroll
            for (int j = 0; j < 4; ++j) p[j] = dot16(kq[j][0], kq[j][1], uu);

            #pragma unroll
            for (int j = 0; j < 4; ++j)
                #pragma unroll
                for (int m = 32; m >= 1; m >>= 1) p[j] += __shfl_xor(p[j], m, 64);
            if (lane == 0) {
                red[4*g+0][s] = p[0]; red[4*g+1][s] = p[1];
                red[4*g+2][s] = p[2]; red[4*g+3][s] = p[3];
            }
            __syncthreads();
            if (tid < 16) {
                float4 rr = *(float4*)&red[tid][0];
                float val = INVN / (rr.x + rr.y + rr.z + rr.w);
                us[tid] = val;
                __hip_atomic_store(&u[base + tid], val, __ATOMIC_RELAXED, __HIP_MEMORY_SCOPE_AGENT);
            }
        }
        gbar(bar, tid, bid);
    }

    // ---- final: P = u[:,None] * K * v[None,:] in place over d_out (fp32 K, exact) ----
    {
        const ull* gp = (const ull*)v;
        ull a = __hip_atomic_load(&gp[2*tid],   __ATOMIC_RELAXED, __HIP_MEMORY_SCOPE_AGENT);
        ull b = __hip_atomic_load(&gp[2*tid+1], __ATOMIC_RELAXED, __HIP_MEMORY_SCOPE_AGENT);
        ull* dst = (ull*)((char*)xs + 16*sgrp(tid));
        dst[0] = a; dst[1] = b;
        __syncthreads();

        const float ur = us[w];                      // wave w scales row base+w
        float4* kp = (float4*)(K + (size_t)(base + w) * NPTS);
        #pragma unroll
        for (int t = 0; t < 16; ++t) {
            int G = t*64 + lane;
            float4 kk = kp[G];
            float4 vv = *(const float4*)((const char*)xs + 16*sgrp(G));
            kk.x *= ur * vv.x; kk.y *= ur * vv.y; kk.z *= ur * vv.z; kk.w *= ur * vv.w;
            kp[G] = kk;
        }
    }
}

// ---------------- non-cooperative fallback kernels (used only if coop launch fails) ----------------
__global__ void __launch_bounds__(1024) stepA_kernel(const float* __restrict__ K,
                                                     const unsigned short* __restrict__ KbT,
                                                     const float* __restrict__ u, float* __restrict__ v,
                                                     int first, int modeA)
{
    const int w = threadIdx.x >> 6, lane = threadIdx.x & 63;
    const int r = blockIdx.x * 16 + w;
    float acc = modeA ? bf16_row_dot(KbT + (size_t)r * NPTS, u, lane, first)
                      : f32_col_dot(K, u, r, lane, first);
    acc = wave_red_sum(acc);
    if (lane == 0) v[r] = INVN / acc;
}

__global__ void __launch_bounds__(1024) stepB_kernel(const float* __restrict__ K,
                                                     const unsigned short* __restrict__ Kb,
                                                     const float* __restrict__ v, float* __restrict__ u,
                                                     int modeB)
{
    const int w = threadIdx.x >> 6, lane = threadIdx.x & 63;
    const int r = blockIdx.x * 16 + w;
    float acc = modeB ? bf16_row_dot(Kb + (size_t)r * NPTS, v, lane, 0)
                      : f32_row_dot(K + (size_t)r * NPTS, v, lane);
    acc = wave_red_sum(acc);
    if (lane == 0) u[r] = INVN / acc;
}

__global__ void __launch_bounds__(1024) final_kernel(float* __restrict__ K,
                                                     const float* __restrict__ u,
                                                     const float* __restrict__ v)
{
    const int w = threadIdx.x >> 6, lane = threadIdx.x & 63;
    const int r = blockIdx.x * 16 + w;
    const float ur = u[r];
    float4* kp = (float4*)(K + (size_t)r * NPTS);
    const float4* vp = (const float4*)v;
    #pragma unroll
    for (int s = 0; s < 16; ++s) {
        int e4 = s * 64 + lane;
        float4 kk = kp[e4], vv = vp[e4];
        kk.x *= ur * vv.x; kk.y *= ur * vv.y; kk.z *= ur * vv.z; kk.w *= ur * vv.w;
        kp[e4] = kk;
    }
}

extern "C" void kernel_launch(void* const* d_in, const int* in_sizes, int n_in,
                              void* d_out, int out_size, void* d_ws, size_t ws_size,
                              hipStream_t stream)
{
    (void)in_sizes; (void)n_in; (void)out_size;
    const float* sn2d  = (const float*)d_in[0];
    const float* sn3d  = (const float*)d_in[1];
    const float* pix2d = (const float*)d_in[2];
    const float* pts3d = (const float*)d_in[3];
    const float* intr  = (const float*)d_in[4];
    const float* W1i = (const float*)d_in[5];  const float* b1i = (const float*)d_in[6];
    const float* W2i = (const float*)d_in[7];  const float* b2i = (const float*)d_in[8];
    const float* W3i = (const float*)d_in[9];  const float* b3i = (const float*)d_in[10];
    const float* W1p = (const float*)d_in[11]; const float* b1p = (const float*)d_in[12];
    const float* W2p = (const float*)d_in[13]; const float* b2p = (const float*)d_in[14];
    const float* W3p = (const float*)d_in[15]; const float* b3p = (const float*)d_in[16];

    float* ws  = (float*)d_ws;
    float* f2d = ws;                       // 4096*128
    float* f3d = f2d + NPTS*FD;            // 4096*128
    float* x2  = f3d + NPTS*FD;            // 4096
    float* y2  = x2 + NPTS;                // 4096
    float* u   = y2 + NPTS;                // 4096
    float* v   = u  + NPTS;                // 4096
    unsigned short* KbT = (unsigned short*)(v + NPTS);   // 33.55 MB
    unsigned short* Kb  = KbT + (size_t)NPTS*NPTS;       // 33.55 MB
    unsigned* bar = (unsigned*)(Kb + (size_t)NPTS*NPTS); // root + 16 group words, 256 B apart
    float* K   = (float*)d_out;            // fp32 K, scaled in place to P at the end

    const size_t base_bytes = (size_t)(2*NPTS*FD + 4*NPTS) * 4;
    const size_t bf16_bytes = (size_t)NPTS * NPTS * 2;
    const size_t need_full  = base_bytes + 2*bf16_bytes + 8192;
    int coop_ok = (ws_size >= need_full) ? 1 : 0;
    int modeA = (ws_size >= base_bytes + bf16_bytes)   ? 1 : 0;
    int modeB = (ws_size >= base_bytes + 2*bf16_bytes) ? 1 : 0;

    feat_kernel<<<dim3(NPTS, 2), 128, 0, stream>>>(sn2d, sn3d, pix2d, pts3d, intr,
        W1i, b1i, W2i, b2i, W3i, b3i, W1p, b1p, W2p, b2p, W3p, b3p,
        f2d, f3d, x2, y2);

    cost_kernel<<<dim3(64, 64), 256, 0, stream>>>(f2d, f3d, x2, y2, K, Kb, KbT,
                                                  coop_ok ? bar : (unsigned*)0,
                                                  modeB, modeA);

    hipError_t err = hipErrorUnknown;
    if (coop_ok) {
        void* args[] = { (void*)&K, (void*)&Kb, (void*)&KbT, (void*)&u, (void*)&v, (void*)&bar };
        err = hipLaunchCooperativeKernel((const void*)sinkhorn_kernel,
                                         dim3(NBLK), dim3(1024), args, SMEM_BYTES, stream);
    }
    if (err != hipSuccess) {
        // non-cooperative fallback: same math, one launch per half-step
        stepA_kernel<<<256, 1024, 0, stream>>>(K, KbT, u, v, 1, modeA);
        for (int i = 0; i < NITER; ++i) {
            stepB_kernel<<<256, 1024, 0, stream>>>(K, Kb, v, u, modeB);
            stepA_kernel<<<256, 1024, 0, stream>>>(K, KbT, u, v, 0, modeA);
        }
        final_kernel<<<256, 1024, 0, stream>>>(K, u, v);
    }
}

// Round 10
// 1557.087 us; speedup vs baseline: 2.5356x; 1.5744x over previous
//
#include <hip/hip_runtime.h>
#include <math.h>

#define NPTS 4096
#define FD   128
#define NITER 200
#define INVN (1.0f / 4096.0f)
#define NBLK 256
#define SMEM_BYTES (NPTS * 4)            // 16 KB swizzled xs

typedef unsigned int uint32;
typedef unsigned long long ull;
typedef unsigned int u32x4 __attribute__((ext_vector_type(4)));

__device__ __forceinline__ float sigmoidf_(float x) { return 1.0f / (1.0f + expf(-x)); }

__device__ __forceinline__ unsigned short f2bf(float f) {
    uint32 x = __float_as_uint(f);
    uint32 r = x + 0x7fffu + ((x >> 16) & 1u);   // RNE; inputs are positive finite
    return (unsigned short)(r >> 16);
}

// float4-group swizzle for xs (16-B granularity)
__device__ __forceinline__ int sgrp(int G) { return G ^ ((G >> 3) & 7); }

// ---- gen-stamped packed pair: floats a,b (low 4 mantissa bits dropped) + 8-bit gen ----
__device__ __forceinline__ ull pack2(float a, float b, unsigned gen) {
    return ((ull)(__float_as_uint(a) >> 4) << 36)
         | ((ull)(__float_as_uint(b) >> 4) << 8)
         | (ull)(gen & 0xFFu);
}
__device__ __forceinline__ float unpA(ull x) { return __uint_as_float(((uint32)(x >> 36)) << 4); }
__device__ __forceinline__ float unpB(ull x) { return __uint_as_float(((uint32)(x >> 8))  << 4); }

__device__ __forceinline__ ull poll_gen(const ull* p, unsigned expect) {
    ull x = __hip_atomic_load(p, __ATOMIC_RELAXED, __HIP_MEMORY_SCOPE_AGENT);
    int gd = 0;
    while ((unsigned)(x & 0xFFu) != expect) {
        __builtin_amdgcn_s_sleep(1);
        x = __hip_atomic_load(p, __ATOMIC_RELAXED, __HIP_MEMORY_SCOPE_AGENT);
        if (++gd > (1 << 24)) break;     // hang insurance only
    }
    return x;
}

// dot of 16 bf16 (2 u32x4) with 16 fp32
__device__ __forceinline__ float dot16(u32x4 a, u32x4 b, const float* uu) {
    float acc = 0.0f;
    #pragma unroll
    for (int q = 0; q < 4; ++q)
        acc += __uint_as_float(a[q] << 16)          * uu[2*q]
             + __uint_as_float(a[q] & 0xffff0000u)  * uu[2*q+1];
    #pragma unroll
    for (int q = 0; q < 4; ++q)
        acc += __uint_as_float(b[q] << 16)          * uu[8 + 2*q]
             + __uint_as_float(b[q] & 0xffff0000u)  * uu[8 + 2*q+1];
    return acc;
}

// helpers for the non-cooperative fallback path
__device__ __forceinline__ float wave_red_sum(float a) {
    #pragma unroll
    for (int m = 32; m >= 1; m >>= 1) a += __shfl_xor(a, m, 64);
    return a;
}

__device__ __forceinline__ float bf16_row_dot(const unsigned short* __restrict__ Krow,
                                              const float* __restrict__ x,
                                              int lane, int first)
{
    const float4* kp = (const float4*)Krow;
    const float4* xp = (const float4*)x;
    float acc = 0.0f;
    #pragma unroll
    for (int s = 0; s < 8; ++s) {
        int i = s*64 + lane;
        float4 kk = kp[i];
        const uint32* kw = (const uint32*)&kk;
        float xx[8];
        if (first) {
            #pragma unroll
            for (int q = 0; q < 8; ++q) xx[q] = 1.0f;
        } else {
            float4 x0 = xp[i*2], x1 = xp[i*2 + 1];
            xx[0]=x0.x; xx[1]=x0.y; xx[2]=x0.z; xx[3]=x0.w;
            xx[4]=x1.x; xx[5]=x1.y; xx[6]=x1.z; xx[7]=x1.w;
        }
        #pragma unroll
        for (int q = 0; q < 4; ++q) {
            acc += __uint_as_float(kw[q] << 16)         * xx[2*q]
                 + __uint_as_float(kw[q] & 0xffff0000u) * xx[2*q+1];
        }
    }
    return acc;
}

__device__ __forceinline__ float f32_row_dot(const float* __restrict__ Krow,
                                             const float* __restrict__ x, int lane)
{
    const float4* kp = (const float4*)Krow;
    const float4* xp = (const float4*)x;
    float acc = 0.0f;
    #pragma unroll
    for (int s = 0; s < 16; ++s) {
        int i = s*64 + lane;
        float4 kk = kp[i], xx = xp[i];
        acc += kk.x*xx.x + kk.y*xx.y + kk.z*xx.z + kk.w*xx.w;
    }
    return acc;
}

__device__ __forceinline__ float f32_col_dot(const float* __restrict__ K,
                                             const float* __restrict__ u,
                                             int col, int lane, int first)
{
    float acc = 0.0f;
    for (int i = lane; i < NPTS; i += 64)
        acc += K[(size_t)i*NPTS + col] * (first ? 1.0f : u[i]);
    return acc;
}

// ---------------- feature MLP kernel: one block (128 thr) per row, side = blockIdx.y ----------------
__global__ void feat_kernel(const float* __restrict__ sn2d, const float* __restrict__ sn3d,
                            const float* __restrict__ pix2d, const float* __restrict__ pts3d,
                            const float* __restrict__ intr,
                            const float* __restrict__ W1i, const float* __restrict__ b1i,
                            const float* __restrict__ W2i, const float* __restrict__ b2i,
                            const float* __restrict__ W3i, const float* __restrict__ b3i,
                            const float* __restrict__ W1p, const float* __restrict__ b1p,
                            const float* __restrict__ W2p, const float* __restrict__ b2p,
                            const float* __restrict__ W3p, const float* __restrict__ b3p,
                            float* __restrict__ f2d, float* __restrict__ f3d,
                            float* __restrict__ x2, float* __restrict__ y2)
{
    const int row  = blockIdx.x;
    const int side = blockIdx.y;
    const int tid  = threadIdx.x;

    __shared__ float xin[6];
    __shared__ float h1s[64];
    __shared__ float h2s[128];
    __shared__ float red[2];

    const float* W1 = side ? W1p : W1i;  const float* B1 = side ? b1p : b1i;
    const float* W2 = side ? W2p : W2i;  const float* B2 = side ? b2p : b2i;
    const float* W3 = side ? W3p : W3i;  const float* B3 = side ? b3p : b3i;

    if (tid == 0) {
        if (side == 0) {
            float a0 = sn2d[row*3+0], a1 = sn2d[row*3+1], a2 = sn2d[row*3+2];
            float n = fmaxf(sqrtf(a0*a0 + a1*a1 + a2*a2), 1e-12f);
            xin[0] = a0/n; xin[1] = a1/n; xin[2] = a2/n;
            float m00 = intr[0], m01 = intr[1], m02 = intr[2];
            float m10 = intr[3], m11 = intr[4], m12 = intr[5];
            float m20 = intr[6], m21 = intr[7], m22 = intr[8];
            float det = m00*(m11*m22 - m12*m21) - m01*(m10*m22 - m12*m20) + m02*(m10*m21 - m11*m20);
            float id = 1.0f/det;
            float i00 = (m11*m22 - m12*m21)*id;
            float i01 = (m02*m21 - m01*m22)*id;
            float i02 = (m01*m12 - m02*m11)*id;
            float i10 = (m12*m20 - m10*m22)*id;
            float i11 = (m00*m22 - m02*m20)*id;
            float i12 = (m02*m10 - m00*m12)*id;
            float i20 = (m10*m21 - m11*m20)*id;
            float i21 = (m01*m20 - m00*m21)*id;
            float i22 = (m00*m11 - m01*m10)*id;
            float px = pix2d[row*2+0], py = pix2d[row*2+1];
            float e0 = i00*px + i01*py + i02;
            float e1 = i10*px + i11*py + i12;
            float e2 = i20*px + i21*py + i22;
            float nb = fmaxf(sqrtf(e0*e0 + e1*e1 + e2*e2), 1e-12f);
            xin[3] = e1/nb; xin[4] = e0/nb; xin[5] = e2/nb;
        } else {
            float a0 = sn3d[row*3+0], a1 = sn3d[row*3+1], a2 = sn3d[row*3+2];
            float n = fmaxf(sqrtf(a0*a0 + a1*a1 + a2*a2), 1e-12f);
            xin[0] = a0/n; xin[1] = a1/n; xin[2] = a2/n;
            float p0 = pts3d[row*3+0], p1 = pts3d[row*3+1], p2 = pts3d[row*3+2];
            float pn = fmaxf(sqrtf(p0*p0 + p1*p1 + p2*p2), 1e-12f);
            xin[3] = p0/pn; xin[4] = p1/pn; xin[5] = p2/pn;
        }
    }
    __syncthreads();
    if (tid < 64) {
        float a = B1[tid];
        #pragma unroll
        for (int k = 0; k < 6; ++k) a += xin[k] * W1[tid*6 + k];
        h1s[tid] = sigmoidf_(a);
    }
    __syncthreads();
    {
        float a = B2[tid];
        #pragma unroll 8
        for (int k = 0; k < 64; ++k) a += h1s[k] * W2[tid*64 + k];
        h2s[tid] = sigmoidf_(a);
    }
    __syncthreads();
    float a = B3[tid];
    #pragma unroll 8
    for (int k = 0; k < 128; ++k) a += h2s[k] * W3[tid*128 + k];
    float o = sigmoidf_(a);

    float ss = o*o;
    #pragma unroll
    for (int m = 32; m >= 1; m >>= 1) ss += __shfl_xor(ss, m, 64);
    if ((tid & 63) == 0) red[tid >> 6] = ss;
    __syncthreads();
    float tot = red[0] + red[1];
    float n = fmaxf(sqrtf(tot), 1e-12f);
    float f = o / n;
    (side ? f3d : f2d)[row*FD + tid] = f;

    float ss2 = f*f;
    #pragma unroll
    for (int m = 32; m >= 1; m >>= 1) ss2 += __shfl_xor(ss2, m, 64);
    __syncthreads();
    if ((tid & 63) == 0) red[tid >> 6] = ss2;
    __syncthreads();
    if (tid == 0) (side ? y2 : x2)[row] = red[0] + red[1];
}

// ---------------- cost kernel: 64x64 tile; writes fp32 K, bf16 Kb (row), bf16 KbT (col), clears stamps ----------------
__global__ void __launch_bounds__(256) cost_kernel(const float* __restrict__ f2d, const float* __restrict__ f3d,
                                                   const float* __restrict__ x2, const float* __restrict__ y2,
                                                   float* __restrict__ K,
                                                   unsigned short* __restrict__ Kb,
                                                   unsigned short* __restrict__ KbT,
                                                   ull* __restrict__ quv,
                                                   int wantB, int wantT)
{
    __shared__ float As[128][64];
    __shared__ float Bs[128][64];
    const int tid = threadIdx.x;
    const int i0 = blockIdx.y * 64;
    const int j0 = blockIdx.x * 64;

    // clear gen-stamped u/v arrays (4096 ulls) so stale stamps never match (incl. 0xAA poison)
    if (quv && blockIdx.y == 0) {
        int idx = blockIdx.x * 256 + tid;
        if (idx < 4096) quv[idx] = 0ull;
    }

    {
        int r0 = tid >> 5;
        int c  = (tid & 31) * 4;
        for (int rr = r0; rr < 64; rr += 8) {
            float4 av = *(const float4*)(f2d + (size_t)(i0+rr)*FD + c);
            As[c+0][rr] = av.x; As[c+1][rr] = av.y; As[c+2][rr] = av.z; As[c+3][rr] = av.w;
            float4 bv = *(const float4*)(f3d + (size_t)(j0+rr)*FD + c);
            Bs[c+0][rr] = bv.x; Bs[c+1][rr] = bv.y; Bs[c+2][rr] = bv.z; Bs[c+3][rr] = bv.w;
        }
    }
    __syncthreads();

    const int tx = tid & 15;
    const int ty = tid >> 4;
    float acc[4][4] = {};
    for (int k = 0; k < 128; ++k) {
        float4 av = *(const float4*)&As[k][ty*4];
        float4 bv = *(const float4*)&Bs[k][tx*4];
        float aa[4] = {av.x, av.y, av.z, av.w};
        float bb[4] = {bv.x, bv.y, bv.z, bv.w};
        #pragma unroll
        for (int i = 0; i < 4; ++i)
            #pragma unroll
            for (int j = 0; j < 4; ++j)
                acc[i][j] += aa[i] * bb[j];
    }

    float kv[4][4];
    #pragma unroll
    for (int i = 0; i < 4; ++i) {
        int gi = i0 + ty*4 + i;
        float xv = x2[gi];
        #pragma unroll
        for (int j = 0; j < 4; ++j) {
            int gj = j0 + tx*4 + j;
            float d2 = xv + y2[gj] - 2.0f * acc[i][j];
            d2 = fmaxf(d2, 1e-12f);
            kv[i][j] = expf(-sqrtf(d2) * 10.0f);
        }
    }

    #pragma unroll
    for (int i = 0; i < 4; ++i) {
        int gi = i0 + ty*4 + i;
        *(float4*)(K + (size_t)gi*NPTS + j0 + tx*4) = make_float4(kv[i][0], kv[i][1], kv[i][2], kv[i][3]);
        if (wantB) {
            uint32 lo = (uint32)f2bf(kv[i][0]) | ((uint32)f2bf(kv[i][1]) << 16);
            uint32 hi = (uint32)f2bf(kv[i][2]) | ((uint32)f2bf(kv[i][3]) << 16);
            uint2 p; p.x = lo; p.y = hi;
            *(uint2*)(Kb + (size_t)gi*NPTS + j0 + tx*4) = p;
        }
    }
    if (wantT) {
        #pragma unroll
        for (int j = 0; j < 4; ++j) {
            int gj = j0 + tx*4 + j;
            uint32 lo = (uint32)f2bf(kv[0][j]) | ((uint32)f2bf(kv[1][j]) << 16);
            uint32 hi = (uint32)f2bf(kv[2][j]) | ((uint32)f2bf(kv[3][j]) << 16);
            uint2 p; p.x = lo; p.y = hi;
            *(uint2*)(KbT + (size_t)gj*NPTS + i0 + ty*4) = p;
        }
    }
}

// ---------------- persistent Sinkhorn v7: registers + gen-stamped dataflow sync (NO barrier) ----------------
// wave w = (g = w>>2 row/col group, s = w&3 slice). Lane l owns elements [s*1024+16l, +16).
// uq/vq: 2048 packed ulls each; entry e = floats (2e, 2e+1) + 8-bit gen. Producing gen-t values
// implies the producer staged the full prior vector, so "all gen-t visible" == grid barrier.
__global__ void __launch_bounds__(1024)
__attribute__((amdgpu_waves_per_eu(4, 4)))
sinkhorn_kernel(float* __restrict__ K,
                const unsigned short* __restrict__ Kb,
                const unsigned short* __restrict__ KbT,
                ull* __restrict__ uq,
                ull* __restrict__ vq)
{
    extern __shared__ char smem[];
    float* xs = (float*)smem;            // 16 KB swizzled u-or-v vector
    __shared__ float red[16][4];
    __shared__ float us[16];

    const int tid  = threadIdx.x;
    const int w    = tid >> 6;
    const int lane = tid & 63;
    const int g    = w >> 2;
    const int s    = w & 3;
    const int bid  = blockIdx.x;
    const int base = bid * 16;

    // one-time: my 4 rows x 1024-elem slice of BOTH Kb and KbT into registers (64 VGPRs)
    u32x4 kq[4][2], kt[4][2];
    #pragma unroll
    for (int j = 0; j < 4; ++j) {
        const size_t off = (size_t)(base + 4*g + j) * NPTS + s*1024 + lane*16;
        const u32x4* kp = (const u32x4*)(Kb  + off);
        const u32x4* tp = (const u32x4*)(KbT + off);
        kq[j][0] = kp[0]; kq[j][1] = kp[1];
        kt[j][0] = tp[0]; kt[j][1] = tp[1];
    }

    for (int it = 0; it <= NITER; ++it) {
        // pin the data tile in VGPRs (loop-carried dep -> no remat; round-9 proven)
        #pragma unroll
        for (int j = 0; j < 4; ++j)
            asm volatile("" : "+v"(kq[j][0]), "+v"(kq[j][1]), "+v"(kt[j][0]), "+v"(kt[j][1]));

        // ---- stage u (or ones) into swizzled xs: thread t owns floats 4t..4t+3 ----
        if (it == 0) {
            *(float4*)((char*)xs + 16*sgrp(tid)) = make_float4(1.f, 1.f, 1.f, 1.f);
        } else {
            unsigned expect = (unsigned)it;                 // u gen stored at it-1 half B = it
            ull a = poll_gen(&uq[2*tid],     expect);
            ull b = poll_gen(&uq[2*tid + 1], expect);
            *(float4*)((char*)xs + 16*sgrp(tid)) = make_float4(unpA(a), unpB(a), unpA(b), unpB(b));
        }
        __syncthreads();

        // ---- half A: v_c = c / dot(K[:,c], u), cols 4g..4g+3 slice s from kt registers ----
        {
            float uu[16];
            #pragma unroll
            for (int k = 0; k < 4; ++k) {
                int G = s*256 + lane*4 + k;
                *(float4*)&uu[4*k] = *(const float4*)((const char*)xs + 16*sgrp(G));
            }
            float p[4];
            #pragma unroll
            for (int j = 0; j < 4; ++j) p[j] = dot16(kt[j][0], kt[j][1], uu);

            #pragma unroll
            for (int j = 0; j < 4; ++j)
                #pragma unroll
                for (int m = 32; m >= 1; m >>= 1) p[j] += __shfl_xor(p[j], m, 64);
            if (lane == 0) {
                red[4*g+0][s] = p[0]; red[4*g+1][s] = p[1];
                red[4*g+2][s] = p[2]; red[4*g+3][s] = p[3];
            }
            __syncthreads();
            if (tid < 8) {
                float4 r0 = *(float4*)&red[2*tid][0];
                float4 r1 = *(float4*)&red[2*tid + 1][0];
                float v0 = INVN / (r0.x + r0.y + r0.z + r0.w);
                float v1 = INVN / (r1.x + r1.y + r1.z + r1.w);
                __hip_atomic_store(&vq[bid*8 + tid], pack2(v0, v1, (unsigned)(it + 1)),
                                   __ATOMIC_RELAXED, __HIP_MEMORY_SCOPE_AGENT);
            }
        }
        if (it == NITER) break;
        __syncthreads();                                    // red[] reuse hazard

        // ---- stage v into swizzled xs (poll gen it+1) ----
        {
            unsigned expect = (unsigned)(it + 1);
            ull a = poll_gen(&vq[2*tid],     expect);
            ull b = poll_gen(&vq[2*tid + 1], expect);
            *(float4*)((char*)xs + 16*sgrp(tid)) = make_float4(unpA(a), unpB(a), unpA(b), unpB(b));
        }
        __syncthreads();

        // ---- half B: u_r = r / dot(K[r,:], v), rows 4g..4g+3 slice s from kq registers ----
        {
            float uu[16];
            #pragma unroll
            for (int k = 0; k < 4; ++k) {
                int G = s*256 + lane*4 + k;
                *(float4*)&uu[4*k] = *(const float4*)((const char*)xs + 16*sgrp(G));
            }
            float p[4];
            #pragma unroll
            for (int j = 0; j < 4; ++j) p[j] = dot16(kq[j][0], kq[j][1], uu);

            #pragma unroll
            for (int j = 0; j < 4; ++j)
                #pragma unroll
                for (int m = 32; m >= 1; m >>= 1) p[j] += __shfl_xor(p[j], m, 64);
            if (lane == 0) {
                red[4*g+0][s] = p[0]; red[4*g+1][s] = p[1];
                red[4*g+2][s] = p[2]; red[4*g+3][s] = p[3];
            }
            __syncthreads();
            if (tid < 8) {
                float4 r0 = *(float4*)&red[2*tid][0];
                float4 r1 = *(float4*)&red[2*tid + 1][0];
                float u0 = INVN / (r0.x + r0.y + r0.z + r0.w);
                float u1 = INVN / (r1.x + r1.y + r1.z + r1.w);
                us[2*tid] = u0; us[2*tid + 1] = u1;
                __hip_atomic_store(&uq[bid*8 + tid], pack2(u0, u1, (unsigned)(it + 1)),
                                   __ATOMIC_RELAXED, __HIP_MEMORY_SCOPE_AGENT);
            }
        }
        __syncthreads();                                    // red[]/us[] ready before next iter
    }

    // ---- final: P = u[:,None] * K * v[None,:] in place over d_out (fp32 K, exact) ----
    {
        unsigned expect = (unsigned)(NITER + 1);
        ull a = poll_gen(&vq[2*tid],     expect);
        ull b = poll_gen(&vq[2*tid + 1], expect);
        *(float4*)((char*)xs + 16*sgrp(tid)) = make_float4(unpA(a), unpB(a), unpA(b), unpB(b));
        __syncthreads();

        const float ur = us[w];                      // wave w scales row base+w (u gen 200)
        float4* kp = (float4*)(K + (size_t)(base + w) * NPTS);
        #pragma unroll
        for (int t = 0; t < 16; ++t) {
            int G = t*64 + lane;
            float4 kk = kp[G];
            float4 vv = *(const float4*)((const char*)xs + 16*sgrp(G));
            kk.x *= ur * vv.x; kk.y *= ur * vv.y; kk.z *= ur * vv.z; kk.w *= ur * vv.w;
            kp[G] = kk;
        }
    }
}

// ---------------- non-cooperative fallback kernels (used only if coop launch fails) ----------------
__global__ void __launch_bounds__(1024) stepA_kernel(const float* __restrict__ K,
                                                     const unsigned short* __restrict__ KbT,
                                                     const float* __restrict__ u, float* __restrict__ v,
                                                     int first, int modeA)
{
    const int w = threadIdx.x >> 6, lane = threadIdx.x & 63;
    const int r = blockIdx.x * 16 + w;
    float acc = modeA ? bf16_row_dot(KbT + (size_t)r * NPTS, u, lane, first)
                      : f32_col_dot(K, u, r, lane, first);
    acc = wave_red_sum(acc);
    if (lane == 0) v[r] = INVN / acc;
}

__global__ void __launch_bounds__(1024) stepB_kernel(const float* __restrict__ K,
                                                     const unsigned short* __restrict__ Kb,
                                                     const float* __restrict__ v, float* __restrict__ u,
                                                     int modeB)
{
    const int w = threadIdx.x >> 6, lane = threadIdx.x & 63;
    const int r = blockIdx.x * 16 + w;
    float acc = modeB ? bf16_row_dot(Kb + (size_t)r * NPTS, v, lane, 0)
                      : f32_row_dot(K + (size_t)r * NPTS, v, lane);
    acc = wave_red_sum(acc);
    if (lane == 0) u[r] = INVN / acc;
}

__global__ void __launch_bounds__(1024) final_kernel(float* __restrict__ K,
                                                     const float* __restrict__ u,
                                                     const float* __restrict__ v)
{
    const int w = threadIdx.x >> 6, lane = threadIdx.x & 63;
    const int r = blockIdx.x * 16 + w;
    const float ur = u[r];
    float4* kp = (float4*)(K + (size_t)r * NPTS);
    const float4* vp = (const float4*)v;
    #pragma unroll
    for (int s = 0; s < 16; ++s) {
        int e4 = s * 64 + lane;
        float4 kk = kp[e4], vv = vp[e4];
        kk.x *= ur * vv.x; kk.y *= ur * vv.y; kk.z *= ur * vv.z; kk.w *= ur * vv.w;
        kp[e4] = kk;
    }
}

extern "C" void kernel_launch(void* const* d_in, const int* in_sizes, int n_in,
                              void* d_out, int out_size, void* d_ws, size_t ws_size,
                              hipStream_t stream)
{
    (void)in_sizes; (void)n_in; (void)out_size;
    const float* sn2d  = (const float*)d_in[0];
    const float* sn3d  = (const float*)d_in[1];
    const float* pix2d = (const float*)d_in[2];
    const float* pts3d = (const float*)d_in[3];
    const float* intr  = (const float*)d_in[4];
    const float* W1i = (const float*)d_in[5];  const float* b1i = (const float*)d_in[6];
    const float* W2i = (const float*)d_in[7];  const float* b2i = (const float*)d_in[8];
    const float* W3i = (const float*)d_in[9];  const float* b3i = (const float*)d_in[10];
    const float* W1p = (const float*)d_in[11]; const float* b1p = (const float*)d_in[12];
    const float* W2p = (const float*)d_in[13]; const float* b2p = (const float*)d_in[14];
    const float* W3p = (const float*)d_in[15]; const float* b3p = (const float*)d_in[16];

    float* ws  = (float*)d_ws;
    float* f2d = ws;                       // 4096*128 fp32
    float* f3d = f2d + NPTS*FD;            // 4096*128 fp32
    float* x2  = f3d + NPTS*FD;            // 4096
    float* y2  = x2 + NPTS;                // 4096
    float* uf  = y2 + NPTS;                // 4096 (fallback path only)
    float* vf  = uf + NPTS;                // 4096 (fallback path only)
    ull*   uq  = (ull*)(vf + NPTS);        // 2048 packed (16 KB)
    ull*   vq  = uq + NPTS/2;              // 2048 packed (16 KB)
    unsigned short* KbT = (unsigned short*)(vq + NPTS/2);  // 33.55 MB
    unsigned short* Kb  = KbT + (size_t)NPTS*NPTS;         // 33.55 MB
    float* K   = (float*)d_out;            // fp32 K, scaled in place to P at the end

    const size_t base_bytes = (size_t)(2*NPTS*FD + 4*NPTS) * 4 + (size_t)2*NPTS*4 + (size_t)NPTS*8;
    const size_t bf16_bytes = (size_t)NPTS * NPTS * 2;
    const size_t need_full  = base_bytes + 2*bf16_bytes;
    int coop_ok = (ws_size >= need_full) ? 1 : 0;
    int modeA = (ws_size >= base_bytes + bf16_bytes)   ? 1 : 0;
    int modeB = (ws_size >= base_bytes + 2*bf16_bytes) ? 1 : 0;

    feat_kernel<<<dim3(NPTS, 2), 128, 0, stream>>>(sn2d, sn3d, pix2d, pts3d, intr,
        W1i, b1i, W2i, b2i, W3i, b3i, W1p, b1p, W2p, b2p, W3p, b3p,
        f2d, f3d, x2, y2);

    cost_kernel<<<dim3(64, 64), 256, 0, stream>>>(f2d, f3d, x2, y2, K, Kb, KbT,
                                                  coop_ok ? uq : (ull*)0,
                                                  modeB, modeA);

    hipError_t err = hipErrorUnknown;
    if (coop_ok) {
        void* args[] = { (void*)&K, (void*)&Kb, (void*)&KbT, (void*)&uq, (void*)&vq };
        err = hipLaunchCooperativeKernel((const void*)sinkhorn_kernel,
                                         dim3(NBLK), dim3(1024), args, SMEM_BYTES, stream);
    }
    if (err != hipSuccess) {
        // non-cooperative fallback: same math, one launch per half-step
        stepA_kernel<<<256, 1024, 0, stream>>>(K, KbT, uf, vf, 1, modeA);
        for (int i = 0; i < NITER; ++i) {
            stepB_kernel<<<256, 1024, 0, stream>>>(K, Kb, vf, uf, modeB);
            stepA_kernel<<<256, 1024, 0, stream>>>(K, KbT, uf, vf, 0, modeA);
        }
        final_kernel<<<256, 1024, 0, stream>>>(K, uf, vf);
    }
}

// Round 11
// 1515.191 us; speedup vs baseline: 2.6057x; 1.0277x over previous
//
#include <hip/hip_runtime.h>
#include <math.h>

#define NPTS 4096
#define FD   128
#define NITER 200
#define INVN (1.0f / 4096.0f)
#define NBLK 256
#define SMEM_BYTES (NPTS * 4)            // 16 KB swizzled xs

typedef unsigned int uint32;
typedef unsigned long long ull;
typedef unsigned int u32x4 __attribute__((ext_vector_type(4)));

__device__ __forceinline__ float sigmoidf_(float x) { return 1.0f / (1.0f + expf(-x)); }

__device__ __forceinline__ unsigned short f2bf(float f) {
    uint32 x = __float_as_uint(f);
    uint32 r = x + 0x7fffu + ((x >> 16) & 1u);   // RNE; inputs are positive finite
    return (unsigned short)(r >> 16);
}

// float4-group swizzle for xs (16-B granularity)
__device__ __forceinline__ int sgrp(int G) { return G ^ ((G >> 3) & 7); }

// ---- gen-stamped packed pair: floats a,b (low 4 mantissa bits dropped) + 8-bit gen ----
__device__ __forceinline__ ull pack2(float a, float b, unsigned gen) {
    return ((ull)(__float_as_uint(a) >> 4) << 36)
         | ((ull)(__float_as_uint(b) >> 4) << 8)
         | (ull)(gen & 0xFFu);
}
__device__ __forceinline__ float unpA(ull x) { return __uint_as_float(((uint32)(x >> 36)) << 4); }
__device__ __forceinline__ float unpB(ull x) { return __uint_as_float(((uint32)(x >> 8))  << 4); }

// poll two stamped words in parallel (both loads in flight before waiting)
__device__ __forceinline__ void poll_gen2(const ull* p0, const ull* p1, unsigned expect,
                                          ull& a, ull& b) {
    a = __hip_atomic_load(p0, __ATOMIC_RELAXED, __HIP_MEMORY_SCOPE_AGENT);
    b = __hip_atomic_load(p1, __ATOMIC_RELAXED, __HIP_MEMORY_SCOPE_AGENT);
    int gd = 0;
    while (((unsigned)(a & 0xFFu) != expect) | ((unsigned)(b & 0xFFu) != expect)) {
        __builtin_amdgcn_s_sleep(1);
        if ((unsigned)(a & 0xFFu) != expect)
            a = __hip_atomic_load(p0, __ATOMIC_RELAXED, __HIP_MEMORY_SCOPE_AGENT);
        if ((unsigned)(b & 0xFFu) != expect)
            b = __hip_atomic_load(p1, __ATOMIC_RELAXED, __HIP_MEMORY_SCOPE_AGENT);
        if (++gd > (1 << 24)) break;     // hang insurance only
    }
}

// canonical GCN 64-lane DPP sum; result valid in lane 63 (AMD crosslane lab-notes sequence)
__device__ __forceinline__ float dpp_sum(float x) {
    asm volatile("v_add_f32 %0, %0, %0 row_shr:1 bound_ctrl:0\n\t"
                 "v_add_f32 %0, %0, %0 row_shr:2 bound_ctrl:0\n\t"
                 "v_add_f32 %0, %0, %0 row_shr:4 bound_ctrl:0\n\t"
                 "v_add_f32 %0, %0, %0 row_shr:8 bound_ctrl:0\n\t"
                 "v_add_f32 %0, %0, %0 row_bcast:15 row_mask:0xa bank_mask:0xf\n\t"
                 "v_add_f32 %0, %0, %0 row_bcast:31 row_mask:0xc bank_mask:0xf"
                 : "+v"(x));
    return x;
}

// dot of 16 bf16 (2 u32x4) with 16 fp32
__device__ __forceinline__ float dot16(u32x4 a, u32x4 b, const float* uu) {
    float acc = 0.0f;
    #pragma unroll
    for (int q = 0; q < 4; ++q)
        acc += __uint_as_float(a[q] << 16)          * uu[2*q]
             + __uint_as_float(a[q] & 0xffff0000u)  * uu[2*q+1];
    #pragma unroll
    for (int q = 0; q < 4; ++q)
        acc += __uint_as_float(b[q] << 16)          * uu[8 + 2*q]
             + __uint_as_float(b[q] & 0xffff0000u)  * uu[8 + 2*q+1];
    return acc;
}

// helpers for the non-cooperative fallback path
__device__ __forceinline__ float wave_red_sum(float a) {
    #pragma unroll
    for (int m = 32; m >= 1; m >>= 1) a += __shfl_xor(a, m, 64);
    return a;
}

__device__ __forceinline__ float bf16_row_dot(const unsigned short* __restrict__ Krow,
                                              const float* __restrict__ x,
                                              int lane, int first)
{
    const float4* kp = (const float4*)Krow;
    const float4* xp = (const float4*)x;
    float acc = 0.0f;
    #pragma unroll
    for (int s = 0; s < 8; ++s) {
        int i = s*64 + lane;
        float4 kk = kp[i];
        const uint32* kw = (const uint32*)&kk;
        float xx[8];
        if (first) {
            #pragma unroll
            for (int q = 0; q < 8; ++q) xx[q] = 1.0f;
        } else {
            float4 x0 = xp[i*2], x1 = xp[i*2 + 1];
            xx[0]=x0.x; xx[1]=x0.y; xx[2]=x0.z; xx[3]=x0.w;
            xx[4]=x1.x; xx[5]=x1.y; xx[6]=x1.z; xx[7]=x1.w;
        }
        #pragma unroll
        for (int q = 0; q < 4; ++q) {
            acc += __uint_as_float(kw[q] << 16)         * xx[2*q]
                 + __uint_as_float(kw[q] & 0xffff0000u) * xx[2*q+1];
        }
    }
    return acc;
}

__device__ __forceinline__ float f32_row_dot(const float* __restrict__ Krow,
                                             const float* __restrict__ x, int lane)
{
    const float4* kp = (const float4*)Krow;
    const float4* xp = (const float4*)x;
    float acc = 0.0f;
    #pragma unroll
    for (int s = 0; s < 16; ++s) {
        int i = s*64 + lane;
        float4 kk = kp[i], xx = xp[i];
        acc += kk.x*xx.x + kk.y*xx.y + kk.z*xx.z + kk.w*xx.w;
    }
    return acc;
}

__device__ __forceinline__ float f32_col_dot(const float* __restrict__ K,
                                             const float* __restrict__ u,
                                             int col, int lane, int first)
{
    float acc = 0.0f;
    for (int i = lane; i < NPTS; i += 64)
        acc += K[(size_t)i*NPTS + col] * (first ? 1.0f : u[i]);
    return acc;
}

// ---------------- feature MLP kernel: one block (128 thr) per row, side = blockIdx.y ----------------
__global__ void feat_kernel(const float* __restrict__ sn2d, const float* __restrict__ sn3d,
                            const float* __restrict__ pix2d, const float* __restrict__ pts3d,
                            const float* __restrict__ intr,
                            const float* __restrict__ W1i, const float* __restrict__ b1i,
                            const float* __restrict__ W2i, const float* __restrict__ b2i,
                            const float* __restrict__ W3i, const float* __restrict__ b3i,
                            const float* __restrict__ W1p, const float* __restrict__ b1p,
                            const float* __restrict__ W2p, const float* __restrict__ b2p,
                            const float* __restrict__ W3p, const float* __restrict__ b3p,
                            float* __restrict__ f2d, float* __restrict__ f3d,
                            float* __restrict__ x2, float* __restrict__ y2)
{
    const int row  = blockIdx.x;
    const int side = blockIdx.y;
    const int tid  = threadIdx.x;

    __shared__ float xin[6];
    __shared__ float h1s[64];
    __shared__ float h2s[128];
    __shared__ float red[2];

    const float* W1 = side ? W1p : W1i;  const float* B1 = side ? b1p : b1i;
    const float* W2 = side ? W2p : W2i;  const float* B2 = side ? b2p : b2i;
    const float* W3 = side ? W3p : W3i;  const float* B3 = side ? b3p : b3i;

    if (tid == 0) {
        if (side == 0) {
            float a0 = sn2d[row*3+0], a1 = sn2d[row*3+1], a2 = sn2d[row*3+2];
            float n = fmaxf(sqrtf(a0*a0 + a1*a1 + a2*a2), 1e-12f);
            xin[0] = a0/n; xin[1] = a1/n; xin[2] = a2/n;
            float m00 = intr[0], m01 = intr[1], m02 = intr[2];
            float m10 = intr[3], m11 = intr[4], m12 = intr[5];
            float m20 = intr[6], m21 = intr[7], m22 = intr[8];
            float det = m00*(m11*m22 - m12*m21) - m01*(m10*m22 - m12*m20) + m02*(m10*m21 - m11*m20);
            float id = 1.0f/det;
            float i00 = (m11*m22 - m12*m21)*id;
            float i01 = (m02*m21 - m01*m22)*id;
            float i02 = (m01*m12 - m02*m11)*id;
            float i10 = (m12*m20 - m10*m22)*id;
            float i11 = (m00*m22 - m02*m20)*id;
            float i12 = (m02*m10 - m00*m12)*id;
            float i20 = (m10*m21 - m11*m20)*id;
            float i21 = (m01*m20 - m00*m21)*id;
            float i22 = (m00*m11 - m01*m10)*id;
            float px = pix2d[row*2+0], py = pix2d[row*2+1];
            float e0 = i00*px + i01*py + i02;
            float e1 = i10*px + i11*py + i12;
            float e2 = i20*px + i21*py + i22;
            float nb = fmaxf(sqrtf(e0*e0 + e1*e1 + e2*e2), 1e-12f);
            xin[3] = e1/nb; xin[4] = e0/nb; xin[5] = e2/nb;
        } else {
            float a0 = sn3d[row*3+0], a1 = sn3d[row*3+1], a2 = sn3d[row*3+2];
            float n = fmaxf(sqrtf(a0*a0 + a1*a1 + a2*a2), 1e-12f);
            xin[0] = a0/n; xin[1] = a1/n; xin[2] = a2/n;
            float p0 = pts3d[row*3+0], p1 = pts3d[row*3+1], p2 = pts3d[row*3+2];
            float pn = fmaxf(sqrtf(p0*p0 + p1*p1 + p2*p2), 1e-12f);
            xin[3] = p0/pn; xin[4] = p1/pn; xin[5] = p2/pn;
        }
    }
    __syncthreads();
    if (tid < 64) {
        float a = B1[tid];
        #pragma unroll
        for (int k = 0; k < 6; ++k) a += xin[k] * W1[tid*6 + k];
        h1s[tid] = sigmoidf_(a);
    }
    __syncthreads();
    {
        float a = B2[tid];
        #pragma unroll 8
        for (int k = 0; k < 64; ++k) a += h1s[k] * W2[tid*64 + k];
        h2s[tid] = sigmoidf_(a);
    }
    __syncthreads();
    float a = B3[tid];
    #pragma unroll 8
    for (int k = 0; k < 128; ++k) a += h2s[k] * W3[tid*128 + k];
    float o = sigmoidf_(a);

    float ss = o*o;
    #pragma unroll
    for (int m = 32; m >= 1; m >>= 1) ss += __shfl_xor(ss, m, 64);
    if ((tid & 63) == 0) red[tid >> 6] = ss;
    __syncthreads();
    float tot = red[0] + red[1];
    float n = fmaxf(sqrtf(tot), 1e-12f);
    float f = o / n;
    (side ? f3d : f2d)[row*FD + tid] = f;

    float ss2 = f*f;
    #pragma unroll
    for (int m = 32; m >= 1; m >>= 1) ss2 += __shfl_xor(ss2, m, 64);
    __syncthreads();
    if ((tid & 63) == 0) red[tid >> 6] = ss2;
    __syncthreads();
    if (tid == 0) (side ? y2 : x2)[row] = red[0] + red[1];
}

// ---------------- cost kernel: 64x64 tile; writes fp32 K, bf16 Kb (row), bf16 KbT (col), clears stamps ----------------
__global__ void __launch_bounds__(256) cost_kernel(const float* __restrict__ f2d, const float* __restrict__ f3d,
                                                   const float* __restrict__ x2, const float* __restrict__ y2,
                                                   float* __restrict__ K,
                                                   unsigned short* __restrict__ Kb,
                                                   unsigned short* __restrict__ KbT,
                                                   ull* __restrict__ quv,
                                                   int wantB, int wantT)
{
    __shared__ float As[128][64];
    __shared__ float Bs[128][64];
    const int tid = threadIdx.x;
    const int i0 = blockIdx.y * 64;
    const int j0 = blockIdx.x * 64;

    // clear gen-stamped u/v arrays (4096 ulls) so stale stamps never match (incl. 0xAA poison)
    if (quv && blockIdx.y == 0) {
        int idx = blockIdx.x * 256 + tid;
        if (idx < 4096) quv[idx] = 0ull;
    }

    {
        int r0 = tid >> 5;
        int c  = (tid & 31) * 4;
        for (int rr = r0; rr < 64; rr += 8) {
            float4 av = *(const float4*)(f2d + (size_t)(i0+rr)*FD + c);
            As[c+0][rr] = av.x; As[c+1][rr] = av.y; As[c+2][rr] = av.z; As[c+3][rr] = av.w;
            float4 bv = *(const float4*)(f3d + (size_t)(j0+rr)*FD + c);
            Bs[c+0][rr] = bv.x; Bs[c+1][rr] = bv.y; Bs[c+2][rr] = bv.z; Bs[c+3][rr] = bv.w;
        }
    }
    __syncthreads();

    const int tx = tid & 15;
    const int ty = tid >> 4;
    float acc[4][4] = {};
    for (int k = 0; k < 128; ++k) {
        float4 av = *(const float4*)&As[k][ty*4];
        float4 bv = *(const float4*)&Bs[k][tx*4];
        float aa[4] = {av.x, av.y, av.z, av.w};
        float bb[4] = {bv.x, bv.y, bv.z, bv.w};
        #pragma unroll
        for (int i = 0; i < 4; ++i)
            #pragma unroll
            for (int j = 0; j < 4; ++j)
                acc[i][j] += aa[i] * bb[j];
    }

    float kv[4][4];
    #pragma unroll
    for (int i = 0; i < 4; ++i) {
        int gi = i0 + ty*4 + i;
        float xv = x2[gi];
        #pragma unroll
        for (int j = 0; j < 4; ++j) {
            int gj = j0 + tx*4 + j;
            float d2 = xv + y2[gj] - 2.0f * acc[i][j];
            d2 = fmaxf(d2, 1e-12f);
            kv[i][j] = expf(-sqrtf(d2) * 10.0f);
        }
    }

    #pragma unroll
    for (int i = 0; i < 4; ++i) {
        int gi = i0 + ty*4 + i;
        *(float4*)(K + (size_t)gi*NPTS + j0 + tx*4) = make_float4(kv[i][0], kv[i][1], kv[i][2], kv[i][3]);
        if (wantB) {
            uint32 lo = (uint32)f2bf(kv[i][0]) | ((uint32)f2bf(kv[i][1]) << 16);
            uint32 hi = (uint32)f2bf(kv[i][2]) | ((uint32)f2bf(kv[i][3]) << 16);
            uint2 p; p.x = lo; p.y = hi;
            *(uint2*)(Kb + (size_t)gi*NPTS + j0 + tx*4) = p;
        }
    }
    if (wantT) {
        #pragma unroll
        for (int j = 0; j < 4; ++j) {
            int gj = j0 + tx*4 + j;
            uint32 lo = (uint32)f2bf(kv[0][j]) | ((uint32)f2bf(kv[1][j]) << 16);
            uint32 hi = (uint32)f2bf(kv[2][j]) | ((uint32)f2bf(kv[3][j]) << 16);
            uint2 p; p.x = lo; p.y = hi;
            *(uint2*)(KbT + (size_t)gj*NPTS + i0 + ty*4) = p;
        }
    }
}

// ---------------- persistent Sinkhorn v8: registers + dataflow sync + DPP reduce, 4 syncs/iter ----------------
// wave w = (g = w>>2 row/col group, s = w&3 slice). Lane l owns elements [s*1024+16l, +16).
__global__ void __launch_bounds__(1024)
__attribute__((amdgpu_waves_per_eu(4, 4)))
sinkhorn_kernel(float* __restrict__ K,
                const unsigned short* __restrict__ Kb,
                const unsigned short* __restrict__ KbT,
                ull* __restrict__ uq,
                ull* __restrict__ vq)
{
    extern __shared__ char smem[];
    float* xs = (float*)smem;            // 16 KB swizzled u-or-v vector
    __shared__ float red[16][4];
    __shared__ float us[16];

    const int tid  = threadIdx.x;
    const int w    = tid >> 6;
    const int lane = tid & 63;
    const int g    = w >> 2;
    const int s    = w & 3;
    const int bid  = blockIdx.x;
    const int base = bid * 16;

    char* xsw = (char*)xs + 16*sgrp(tid);          // this thread's staging slot
    int uoff[4];
    #pragma unroll
    for (int k = 0; k < 4; ++k) uoff[k] = 16*sgrp(s*256 + lane*4 + k);

    // one-time: my 4 rows x 1024-elem slice of BOTH Kb and KbT into registers (64 VGPRs)
    u32x4 kq[4][2], kt[4][2];
    #pragma unroll
    for (int j = 0; j < 4; ++j) {
        const size_t off = (size_t)(base + 4*g + j) * NPTS + s*1024 + lane*16;
        const u32x4* kp = (const u32x4*)(Kb  + off);
        const u32x4* tp = (const u32x4*)(KbT + off);
        kq[j][0] = kp[0]; kq[j][1] = kp[1];
        kt[j][0] = tp[0]; kt[j][1] = tp[1];
    }

    for (int it = 0; it <= NITER; ++it) {
        // pin the data tile in VGPRs (loop-carried dep -> no remat; round-9 proven)
        #pragma unroll
        for (int j = 0; j < 4; ++j)
            asm volatile("" : "+v"(kq[j][0]), "+v"(kq[j][1]), "+v"(kt[j][0]), "+v"(kt[j][1]));

        // ---- stage u (or ones) into swizzled xs ----
        if (it == 0) {
            *(float4*)xsw = make_float4(1.f, 1.f, 1.f, 1.f);
        } else {
            ull a, b;
            poll_gen2(&uq[2*tid], &uq[2*tid + 1], (unsigned)it, a, b);
            *(float4*)xsw = make_float4(unpA(a), unpB(a), unpA(b), unpB(b));
        }
        __syncthreads();                                    // S1: xs ready (also orders red reuse)

        // ---- half A: v_c = c / dot(K[:,c], u), cols 4g..4g+3 slice s from kt registers ----
        {
            float uu[16];
            #pragma unroll
            for (int k = 0; k < 4; ++k)
                *(float4*)&uu[4*k] = *(const float4*)((const char*)xs + uoff[k]);
            float p[4];
            #pragma unroll
            for (int j = 0; j < 4; ++j) p[j] = dpp_sum(dot16(kt[j][0], kt[j][1], uu));
            if (lane == 63) {
                red[4*g+0][s] = p[0]; red[4*g+1][s] = p[1];
                red[4*g+2][s] = p[2]; red[4*g+3][s] = p[3];
            }
            __syncthreads();                                // S2: red complete
            if (tid < 8) {
                float4 r0 = *(float4*)&red[2*tid][0];
                float4 r1 = *(float4*)&red[2*tid + 1][0];
                float v0 = INVN / (r0.x + r0.y + r0.z + r0.w);
                float v1 = INVN / (r1.x + r1.y + r1.z + r1.w);
                __hip_atomic_store(&vq[bid*8 + tid], pack2(v0, v1, (unsigned)(it + 1)),
                                   __ATOMIC_RELAXED, __HIP_MEMORY_SCOPE_AGENT);
            }
        }
        if (it == NITER) break;

        // ---- stage v into swizzled xs (poll gen it+1); S3 orders red reuse for half B ----
        {
            ull a, b;
            poll_gen2(&vq[2*tid], &vq[2*tid + 1], (unsigned)(it + 1), a, b);
            *(float4*)xsw = make_float4(unpA(a), unpB(a), unpA(b), unpB(b));
        }
        __syncthreads();                                    // S3: xs ready

        // ---- half B: u_r = r / dot(K[r,:], v), rows 4g..4g+3 slice s from kq registers ----
        {
            float uu[16];
            #pragma unroll
            for (int k = 0; k < 4; ++k)
                *(float4*)&uu[4*k] = *(const float4*)((const char*)xs + uoff[k]);
            float p[4];
            #pragma unroll
            for (int j = 0; j < 4; ++j) p[j] = dpp_sum(dot16(kq[j][0], kq[j][1], uu));
            if (lane == 63) {
                red[4*g+0][s] = p[0]; red[4*g+1][s] = p[1];
                red[4*g+2][s] = p[2]; red[4*g+3][s] = p[3];
            }
            __syncthreads();                                // S4: red complete
            if (tid < 8) {
                float4 r0 = *(float4*)&red[2*tid][0];
                float4 r1 = *(float4*)&red[2*tid + 1][0];
                float u0 = INVN / (r0.x + r0.y + r0.z + r0.w);
                float u1 = INVN / (r1.x + r1.y + r1.z + r1.w);
                us[2*tid] = u0; us[2*tid + 1] = u1;
                __hip_atomic_store(&uq[bid*8 + tid], pack2(u0, u1, (unsigned)(it + 1)),
                                   __ATOMIC_RELAXED, __HIP_MEMORY_SCOPE_AGENT);
            }
        }
        // next iter's S1 orders red/us reuse — no extra sync needed
    }

    // ---- final: P = u[:,None] * K * v[None,:] in place over d_out (fp32 K, exact) ----
    {
        ull a, b;
        poll_gen2(&vq[2*tid], &vq[2*tid + 1], (unsigned)(NITER + 1), a, b);
        *(float4*)xsw = make_float4(unpA(a), unpB(a), unpA(b), unpB(b));
        __syncthreads();

        const float ur = us[w];                      // wave w scales row base+w (u gen 200)
        float4* kp = (float4*)(K + (size_t)(base + w) * NPTS);
        #pragma unroll
        for (int t = 0; t < 16; ++t) {
            int G = t*64 + lane;
            float4 kk = kp[G];
            float4 vv = *(const float4*)((const char*)xs + 16*sgrp(G));
            kk.x *= ur * vv.x; kk.y *= ur * vv.y; kk.z *= ur * vv.z; kk.w *= ur * vv.w;
            kp[G] = kk;
        }
    }
}

// ---------------- non-cooperative fallback kernels (used only if coop launch fails) ----------------
__global__ void __launch_bounds__(1024) stepA_kernel(const float* __restrict__ K,
                                                     const unsigned short* __restrict__ KbT,
                                                     const float* __restrict__ u, float* __restrict__ v,
                                                     int first, int modeA)
{
    const int w = threadIdx.x >> 6, lane = threadIdx.x & 63;
    const int r = blockIdx.x * 16 + w;
    float acc = modeA ? bf16_row_dot(KbT + (size_t)r * NPTS, u, lane, first)
                      : f32_col_dot(K, u, r, lane, first);
    acc = wave_red_sum(acc);
    if (lane == 0) v[r] = INVN / acc;
}

__global__ void __launch_bounds__(1024) stepB_kernel(const float* __restrict__ K,
                                                     const unsigned short* __restrict__ Kb,
                                                     const float* __restrict__ v, float* __restrict__ u,
                                                     int modeB)
{
    const int w = threadIdx.x >> 6, lane = threadIdx.x & 63;
    const int r = blockIdx.x * 16 + w;
    float acc = modeB ? bf16_row_dot(Kb + (size_t)r * NPTS, v, lane, 0)
                      : f32_row_dot(K + (size_t)r * NPTS, v, lane);
    acc = wave_red_sum(acc);
    if (lane == 0) u[r] = INVN / acc;
}

__global__ void __launch_bounds__(1024) final_kernel(float* __restrict__ K,
                                                     const float* __restrict__ u,
                                                     const float* __restrict__ v)
{
    const int w = threadIdx.x >> 6, lane = threadIdx.x & 63;
    const int r = blockIdx.x * 16 + w;
    const float ur = u[r];
    float4* kp = (float4*)(K + (size_t)r * NPTS);
    const float4* vp = (const float4*)v;
    #pragma unroll
    for (int s = 0; s < 16; ++s) {
        int e4 = s * 64 + lane;
        float4 kk = kp[e4], vv = vp[e4];
        kk.x *= ur * vv.x; kk.y *= ur * vv.y; kk.z *= ur * vv.z; kk.w *= ur * vv.w;
        kp[e4] = kk;
    }
}

extern "C" void kernel_launch(void* const* d_in, const int* in_sizes, int n_in,
                              void* d_out, int out_size, void* d_ws, size_t ws_size,
                              hipStream_t stream)
{
    (void)in_sizes; (void)n_in; (void)out_size;
    const float* sn2d  = (const float*)d_in[0];
    const float* sn3d  = (const float*)d_in[1];
    const float* pix2d = (const float*)d_in[2];
    const float* pts3d = (const float*)d_in[3];
    const float* intr  = (const float*)d_in[4];
    const float* W1i = (const float*)d_in[5];  const float* b1i = (const float*)d_in[6];
    const float* W2i = (const float*)d_in[7];  const float* b2i = (const float*)d_in[8];
    const float* W3i = (const float*)d_in[9];  const float* b3i = (const float*)d_in[10];
    const float* W1p = (const float*)d_in[11]; const float* b1p = (const float*)d_in[12];
    const float* W2p = (const float*)d_in[13]; const float* b2p = (const float*)d_in[14];
    const float* W3p = (const float*)d_in[15]; const float* b3p = (const float*)d_in[16];

    float* ws  = (float*)d_ws;
    float* f2d = ws;                       // 4096*128 fp32
    float* f3d = f2d + NPTS*FD;            // 4096*128 fp32
    float* x2  = f3d + NPTS*FD;            // 4096
    float* y2  = x2 + NPTS;                // 4096
    float* uf  = y2 + NPTS;                // 4096 (fallback path only)
    float* vf  = uf + NPTS;                // 4096 (fallback path only)
    ull*   uq  = (ull*)(vf + NPTS);        // 2048 packed (16 KB)
    ull*   vq  = uq + NPTS/2;              // 2048 packed (16 KB)
    unsigned short* KbT = (unsigned short*)(vq + NPTS/2);  // 33.55 MB
    unsigned short* Kb  = KbT + (size_t)NPTS*NPTS;         // 33.55 MB
    float* K   = (float*)d_out;            // fp32 K, scaled in place to P at the end

    const size_t base_bytes = (size_t)(2*NPTS*FD + 4*NPTS) * 4 + (size_t)2*NPTS*4 + (size_t)NPTS*8;
    const size_t bf16_bytes = (size_t)NPTS * NPTS * 2;
    const size_t need_full  = base_bytes + 2*bf16_bytes;
    int coop_ok = (ws_size >= need_full) ? 1 : 0;
    int modeA = (ws_size >= base_bytes + bf16_bytes)   ? 1 : 0;
    int modeB = (ws_size >= base_bytes + 2*bf16_bytes) ? 1 : 0;

    feat_kernel<<<dim3(NPTS, 2), 128, 0, stream>>>(sn2d, sn3d, pix2d, pts3d, intr,
        W1i, b1i, W2i, b2i, W3i, b3i, W1p, b1p, W2p, b2p, W3p, b3p,
        f2d, f3d, x2, y2);

    cost_kernel<<<dim3(64, 64), 256, 0, stream>>>(f2d, f3d, x2, y2, K, Kb, KbT,
                                                  coop_ok ? uq : (ull*)0,
                                                  modeB, modeA);

    hipError_t err = hipErrorUnknown;
    if (coop_ok) {
        void* args[] = { (void*)&K, (void*)&Kb, (void*)&KbT, (void*)&uq, (void*)&vq };
        err = hipLaunchCooperativeKernel((const void*)sinkhorn_kernel,
                                         dim3(NBLK), dim3(1024), args, SMEM_BYTES, stream);
    }
    if (err != hipSuccess) {
        // non-cooperative fallback: same math, one launch per half-step
        stepA_kernel<<<256, 1024, 0, stream>>>(K, KbT, uf, vf, 1, modeA);
        for (int i = 0; i < NITER; ++i) {
            stepB_kernel<<<256, 1024, 0, stream>>>(K, Kb, vf, uf, modeB);
            stepA_kernel<<<256, 1024, 0, stream>>>(K, KbT, uf, vf, 0, modeA);
        }
        final_kernel<<<256, 1024, 0, stream>>>(K, uf, vf);
    }
}

// Round 13
// 1442.549 us; speedup vs baseline: 2.7369x; 1.0504x over previous
//
#include <hip/hip_runtime.h>
#include <math.h>

#define NPTS 4096
#define FD   128
#define NITER 200
#define INVN (1.0f / 4096.0f)
#define NBLK 256
#define XSCALE 1024.0f
#define FINC 0.25f                        // (XSCALE / 4096): v = FINC / scaled_sum
#define SMEM_BYTES (NPTS * 4)             // 16 KB: f16 xs uses first 8 KB; final fp32 phase uses all

typedef unsigned int uint32;
typedef unsigned long long ull;
typedef unsigned int u32x4 __attribute__((ext_vector_type(4)));
typedef __fp16 h2v __attribute__((ext_vector_type(2)));   // clang's native half2 (matches amdgcn builtins)

__device__ __forceinline__ float sigmoidf_(float x) { return 1.0f / (1.0f + expf(-x)); }

// pack two fp32 -> 2xf16 (RTZ) in one u32
__device__ __forceinline__ uint32 pkh(float a, float b) {
    h2v h = __builtin_amdgcn_cvt_pkrtz(a, b);
    return __builtin_bit_cast(uint32, h);
}

// fp32 16B-granule swizzle (final phase only)
__device__ __forceinline__ int sgrp(int G) { return G ^ ((G >> 3) & 7); }
// f16 16B-granule swizzle (iteration phase; 512 granules)
__device__ __forceinline__ int swz2(int G) { return G ^ ((G >> 2) & 3); }

// ---- gen-stamped packed pair: floats a,b (low 4 mantissa bits dropped) + 8-bit gen ----
__device__ __forceinline__ ull pack2(float a, float b, unsigned gen) {
    return ((ull)(__float_as_uint(a) >> 4) << 36)
         | ((ull)(__float_as_uint(b) >> 4) << 8)
         | (ull)(gen & 0xFFu);
}
__device__ __forceinline__ float unpA(ull x) { return __uint_as_float(((uint32)(x >> 36)) << 4); }
__device__ __forceinline__ float unpB(ull x) { return __uint_as_float(((uint32)(x >> 8))  << 4); }
// scaled variants: multiply by 1024 via exponent add (values are positive normals)
__device__ __forceinline__ float unpAs(ull x) { return __uint_as_float((((uint32)(x >> 36)) << 4) + (10u << 23)); }
__device__ __forceinline__ float unpBs(ull x) { return __uint_as_float((((uint32)(x >> 8))  << 4) + (10u << 23)); }

// poll two stamped words in parallel (both loads in flight before waiting)
__device__ __forceinline__ void poll_gen2(const ull* p0, const ull* p1, unsigned expect,
                                          ull& a, ull& b) {
    a = __hip_atomic_load(p0, __ATOMIC_RELAXED, __HIP_MEMORY_SCOPE_AGENT);
    b = __hip_atomic_load(p1, __ATOMIC_RELAXED, __HIP_MEMORY_SCOPE_AGENT);
    int gd = 0;
    while (((unsigned)(a & 0xFFu) != expect) | ((unsigned)(b & 0xFFu) != expect)) {
        __builtin_amdgcn_s_sleep(1);
        if ((unsigned)(a & 0xFFu) != expect)
            a = __hip_atomic_load(p0, __ATOMIC_RELAXED, __HIP_MEMORY_SCOPE_AGENT);
        if ((unsigned)(b & 0xFFu) != expect)
            b = __hip_atomic_load(p1, __ATOMIC_RELAXED, __HIP_MEMORY_SCOPE_AGENT);
        if (++gd > (1 << 24)) break;     // hang insurance only
    }
}

// canonical GCN 64-lane DPP sum; result valid in lane 63
__device__ __forceinline__ float dpp_sum(float x) {
    asm volatile("v_add_f32 %0, %0, %0 row_shr:1 bound_ctrl:0\n\t"
                 "v_add_f32 %0, %0, %0 row_shr:2 bound_ctrl:0\n\t"
                 "v_add_f32 %0, %0, %0 row_shr:4 bound_ctrl:0\n\t"
                 "v_add_f32 %0, %0, %0 row_shr:8 bound_ctrl:0\n\t"
                 "v_add_f32 %0, %0, %0 row_bcast:15 row_mask:0xa bank_mask:0xf\n\t"
                 "v_add_f32 %0, %0, %0 row_bcast:31 row_mask:0xc bank_mask:0xf"
                 : "+v"(x));
    return x;
}

// dot of 16 f16 K elems (2 u32x4) with 16 f16 x elems (2 u32x4) via v_dot2_f32_f16
__device__ __forceinline__ float dot16h(u32x4 a, u32x4 b, u32x4 x0, u32x4 x1) {
    float acc = 0.0f;
    #pragma unroll
    for (int q = 0; q < 4; ++q)
        acc = __builtin_amdgcn_fdot2(__builtin_bit_cast(h2v, a[q]),
                                     __builtin_bit_cast(h2v, x0[q]), acc, false);
    #pragma unroll
    for (int q = 0; q < 4; ++q)
        acc = __builtin_amdgcn_fdot2(__builtin_bit_cast(h2v, b[q]),
                                     __builtin_bit_cast(h2v, x1[q]), acc, false);
    return acc;
}

// helpers for the non-cooperative fallback path (fp32 K only)
__device__ __forceinline__ float wave_red_sum(float a) {
    #pragma unroll
    for (int m = 32; m >= 1; m >>= 1) a += __shfl_xor(a, m, 64);
    return a;
}

__device__ __forceinline__ float f32_row_dot(const float* __restrict__ Krow,
                                             const float* __restrict__ x, int lane)
{
    const float4* kp = (const float4*)Krow;
    const float4* xp = (const float4*)x;
    float acc = 0.0f;
    #pragma unroll
    for (int s = 0; s < 16; ++s) {
        int i = s*64 + lane;
        float4 kk = kp[i], xx = xp[i];
        acc += kk.x*xx.x + kk.y*xx.y + kk.z*xx.z + kk.w*xx.w;
    }
    return acc;
}

__device__ __forceinline__ float f32_col_dot(const float* __restrict__ K,
                                             const float* __restrict__ u,
                                             int col, int lane, int first)
{
    float acc = 0.0f;
    for (int i = lane; i < NPTS; i += 64)
        acc += K[(size_t)i*NPTS + col] * (first ? 1.0f : u[i]);
    return acc;
}

// ---------------- feature MLP kernel: one block (128 thr) per row, side = blockIdx.y ----------------
__global__ void feat_kernel(const float* __restrict__ sn2d, const float* __restrict__ sn3d,
                            const float* __restrict__ pix2d, const float* __restrict__ pts3d,
                            const float* __restrict__ intr,
                            const float* __restrict__ W1i, const float* __restrict__ b1i,
                            const float* __restrict__ W2i, const float* __restrict__ b2i,
                            const float* __restrict__ W3i, const float* __restrict__ b3i,
                            const float* __restrict__ W1p, const float* __restrict__ b1p,
                            const float* __restrict__ W2p, const float* __restrict__ b2p,
                            const float* __restrict__ W3p, const float* __restrict__ b3p,
                            float* __restrict__ f2d, float* __restrict__ f3d,
                            float* __restrict__ x2, float* __restrict__ y2)
{
    const int row  = blockIdx.x;
    const int side = blockIdx.y;
    const int tid  = threadIdx.x;

    __shared__ float xin[6];
    __shared__ float h1s[64];
    __shared__ float h2s[128];
    __shared__ float red[2];

    const float* W1 = side ? W1p : W1i;  const float* B1 = side ? b1p : b1i;
    const float* W2 = side ? W2p : W2i;  const float* B2 = side ? b2p : b2i;
    const float* W3 = side ? W3p : W3i;  const float* B3 = side ? b3p : b3i;

    if (tid == 0) {
        if (side == 0) {
            float a0 = sn2d[row*3+0], a1 = sn2d[row*3+1], a2 = sn2d[row*3+2];
            float n = fmaxf(sqrtf(a0*a0 + a1*a1 + a2*a2), 1e-12f);
            xin[0] = a0/n; xin[1] = a1/n; xin[2] = a2/n;
            float m00 = intr[0], m01 = intr[1], m02 = intr[2];
            float m10 = intr[3], m11 = intr[4], m12 = intr[5];
            float m20 = intr[6], m21 = intr[7], m22 = intr[8];
            float det = m00*(m11*m22 - m12*m21) - m01*(m10*m22 - m12*m20) + m02*(m10*m21 - m11*m20);
            float id = 1.0f/det;
            float i00 = (m11*m22 - m12*m21)*id;
            float i01 = (m02*m21 - m01*m22)*id;
            float i02 = (m01*m12 - m02*m11)*id;
            float i10 = (m12*m20 - m10*m22)*id;
            float i11 = (m00*m22 - m02*m20)*id;
            float i12 = (m02*m10 - m00*m12)*id;
            float i20 = (m10*m21 - m11*m20)*id;
            float i21 = (m01*m20 - m00*m21)*id;
            float i22 = (m00*m11 - m01*m10)*id;
            float px = pix2d[row*2+0], py = pix2d[row*2+1];
            float e0 = i00*px + i01*py + i02;
            float e1 = i10*px + i11*py + i12;
            float e2 = i20*px + i21*py + i22;
            float nb = fmaxf(sqrtf(e0*e0 + e1*e1 + e2*e2), 1e-12f);
            xin[3] = e1/nb; xin[4] = e0/nb; xin[5] = e2/nb;
        } else {
            float a0 = sn3d[row*3+0], a1 = sn3d[row*3+1], a2 = sn3d[row*3+2];
            float n = fmaxf(sqrtf(a0*a0 + a1*a1 + a2*a2), 1e-12f);
            xin[0] = a0/n; xin[1] = a1/n; xin[2] = a2/n;
            float p0 = pts3d[row*3+0], p1 = pts3d[row*3+1], p2 = pts3d[row*3+2];
            float pn = fmaxf(sqrtf(p0*p0 + p1*p1 + p2*p2), 1e-12f);
            xin[3] = p0/pn; xin[4] = p1/pn; xin[5] = p2/pn;
        }
    }
    __syncthreads();
    if (tid < 64) {
        float a = B1[tid];
        #pragma unroll
        for (int k = 0; k < 6; ++k) a += xin[k] * W1[tid*6 + k];
        h1s[tid] = sigmoidf_(a);
    }
    __syncthreads();
    {
        float a = B2[tid];
        #pragma unroll 8
        for (int k = 0; k < 64; ++k) a += h1s[k] * W2[tid*64 + k];
        h2s[tid] = sigmoidf_(a);
    }
    __syncthreads();
    float a = B3[tid];
    #pragma unroll 8
    for (int k = 0; k < 128; ++k) a += h2s[k] * W3[tid*128 + k];
    float o = sigmoidf_(a);

    float ss = o*o;
    #pragma unroll
    for (int m = 32; m >= 1; m >>= 1) ss += __shfl_xor(ss, m, 64);
    if ((tid & 63) == 0) red[tid >> 6] = ss;
    __syncthreads();
    float tot = red[0] + red[1];
    float n = fmaxf(sqrtf(tot), 1e-12f);
    float f = o / n;
    (side ? f3d : f2d)[row*FD + tid] = f;

    float ss2 = f*f;
    #pragma unroll
    for (int m = 32; m >= 1; m >>= 1) ss2 += __shfl_xor(ss2, m, 64);
    __syncthreads();
    if ((tid & 63) == 0) red[tid >> 6] = ss2;
    __syncthreads();
    if (tid == 0) (side ? y2 : x2)[row] = red[0] + red[1];
}

// ---------------- cost kernel: 64x64 tile; writes fp32 K, f16 Kb (row), f16 KbT (col), clears stamps ----------------
__global__ void __launch_bounds__(256) cost_kernel(const float* __restrict__ f2d, const float* __restrict__ f3d,
                                                   const float* __restrict__ x2, const float* __restrict__ y2,
                                                   float* __restrict__ K,
                                                   unsigned short* __restrict__ Kb,
                                                   unsigned short* __restrict__ KbT,
                                                   ull* __restrict__ quv,
                                                   int wantB, int wantT)
{
    __shared__ float As[128][64];
    __shared__ float Bs[128][64];
    const int tid = threadIdx.x;
    const int i0 = blockIdx.y * 64;
    const int j0 = blockIdx.x * 64;

    // clear gen-stamped u/v arrays (4096 ulls) so stale stamps never match (incl. 0xAA poison)
    if (quv && blockIdx.y == 0) {
        int idx = blockIdx.x * 256 + tid;
        if (idx < 4096) quv[idx] = 0ull;
    }

    {
        int r0 = tid >> 5;
        int c  = (tid & 31) * 4;
        for (int rr = r0; rr < 64; rr += 8) {
            float4 av = *(const float4*)(f2d + (size_t)(i0+rr)*FD + c);
            As[c+0][rr] = av.x; As[c+1][rr] = av.y; As[c+2][rr] = av.z; As[c+3][rr] = av.w;
            float4 bv = *(const float4*)(f3d + (size_t)(j0+rr)*FD + c);
            Bs[c+0][rr] = bv.x; Bs[c+1][rr] = bv.y; Bs[c+2][rr] = bv.z; Bs[c+3][rr] = bv.w;
        }
    }
    __syncthreads();

    const int tx = tid & 15;
    const int ty = tid >> 4;
    float acc[4][4] = {};
    for (int k = 0; k < 128; ++k) {
        float4 av = *(const float4*)&As[k][ty*4];
        float4 bv = *(const float4*)&Bs[k][tx*4];
        float aa[4] = {av.x, av.y, av.z, av.w};
        float bb[4] = {bv.x, bv.y, bv.z, bv.w};
        #pragma unroll
        for (int i = 0; i < 4; ++i)
            #pragma unroll
            for (int j = 0; j < 4; ++j)
                acc[i][j] += aa[i] * bb[j];
    }

    float kv[4][4];
    #pragma unroll
    for (int i = 0; i < 4; ++i) {
        int gi = i0 + ty*4 + i;
        float xv = x2[gi];
        #pragma unroll
        for (int j = 0; j < 4; ++j) {
            int gj = j0 + tx*4 + j;
            float d2 = xv + y2[gj] - 2.0f * acc[i][j];
            d2 = fmaxf(d2, 1e-12f);
            kv[i][j] = expf(-sqrtf(d2) * 10.0f);
        }
    }

    #pragma unroll
    for (int i = 0; i < 4; ++i) {
        int gi = i0 + ty*4 + i;
        *(float4*)(K + (size_t)gi*NPTS + j0 + tx*4) = make_float4(kv[i][0], kv[i][1], kv[i][2], kv[i][3]);
        if (wantB) {
            uint2 p; p.x = pkh(kv[i][0], kv[i][1]); p.y = pkh(kv[i][2], kv[i][3]);
            *(uint2*)(Kb + (size_t)gi*NPTS + j0 + tx*4) = p;
        }
    }
    if (wantT) {
        #pragma unroll
        for (int j = 0; j < 4; ++j) {
            int gj = j0 + tx*4 + j;
            uint2 p; p.x = pkh(kv[0][j], kv[1][j]); p.y = pkh(kv[2][j], kv[3][j]);
            *(uint2*)(KbT + (size_t)gj*NPTS + i0 + ty*4) = p;
        }
    }
}

// ---------------- persistent Sinkhorn v9: f16 registers + fdot2 + dataflow sync + DPP ----------------
// wave w = (g = w>>2 row/col group, s = w&3 slice). Lane l owns elements [s*1024+16l, +16).
__global__ void __launch_bounds__(1024)
__attribute__((amdgpu_waves_per_eu(4, 4)))
sinkhorn_kernel(float* __restrict__ K,
                const unsigned short* __restrict__ Kb,
                const unsigned short* __restrict__ KbT,
                ull* __restrict__ uq,
                ull* __restrict__ vq)
{
    extern __shared__ char smem[];
    float* xs = (float*)smem;            // iteration: first 8 KB = f16-packed x; final: 16 KB fp32
    __shared__ float red[16][4];
    __shared__ float us[16];

    const int tid  = threadIdx.x;
    const int w    = tid >> 6;
    const int lane = tid & 63;
    const int g    = w >> 2;
    const int s    = w & 3;
    const int bid  = blockIdx.x;
    const int base = bid * 16;

    // f16 staging slot: thread t owns elems 4t..4t+3 = granule t>>1, half t&1
    char* xsw2 = (char*)xs + 16*swz2(tid >> 1) + 8*(tid & 1);
    // f16 read offsets: lane's 16 elems = granules (s*128+2l, +1)
    const int xoff0 = 16*swz2(s*128 + 2*lane);
    const int xoff1 = 16*swz2(s*128 + 2*lane + 1);

    // one-time: my 4 rows x 1024-elem f16 slice of BOTH Kb and KbT into registers (64 VGPRs)
    u32x4 kq[4][2], kt[4][2];
    #pragma unroll
    for (int j = 0; j < 4; ++j) {
        const size_t off = (size_t)(base + 4*g + j) * NPTS + s*1024 + lane*16;
        const u32x4* kp = (const u32x4*)(Kb  + off);
        const u32x4* tp = (const u32x4*)(KbT + off);
        kq[j][0] = kp[0]; kq[j][1] = kp[1];
        kt[j][0] = tp[0]; kt[j][1] = tp[1];
    }

    for (int it = 0; it <= NITER; ++it) {
        // pin the data tile in VGPRs (loop-carried dep -> no remat; round-9 proven)
        #pragma unroll
        for (int j = 0; j < 4; ++j)
            asm volatile("" : "+v"(kq[j][0]), "+v"(kq[j][1]), "+v"(kt[j][0]), "+v"(kt[j][1]));

        // ---- stage u (or ones), scaled by 1024, as packed f16 into xs ----
        if (it == 0) {
            uint32 o1 = pkh(XSCALE, XSCALE);
            *(ull*)xsw2 = ((ull)o1 << 32) | o1;
        } else {
            ull a, b;
            poll_gen2(&uq[2*tid], &uq[2*tid + 1], (unsigned)it, a, b);
            float f0 = fminf(unpAs(a), 60000.f), f1 = fminf(unpBs(a), 60000.f);
            float f2 = fminf(unpAs(b), 60000.f), f3 = fminf(unpBs(b), 60000.f);
            uint32 w0 = pkh(f0, f1), w1 = pkh(f2, f3);
            *(ull*)xsw2 = ((ull)w1 << 32) | w0;
        }
        __syncthreads();                                    // S1: xs ready (also orders red reuse)

        // ---- half A: v_c = FINC / Σ K[:,c]·(u·S), cols 4g..4g+3 slice s from kt registers ----
        {
            u32x4 x0 = *(const u32x4*)((const char*)xs + xoff0);
            u32x4 x1 = *(const u32x4*)((const char*)xs + xoff1);
            float p[4];
            #pragma unroll
            for (int j = 0; j < 4; ++j) p[j] = dpp_sum(dot16h(kt[j][0], kt[j][1], x0, x1));
            if (lane == 63) {
                red[4*g+0][s] = p[0]; red[4*g+1][s] = p[1];
                red[4*g+2][s] = p[2]; red[4*g+3][s] = p[3];
            }
            __syncthreads();                                // S2: red complete
            if (tid < 8) {
                float4 r0 = *(float4*)&red[2*tid][0];
                float4 r1 = *(float4*)&red[2*tid + 1][0];
                float v0 = FINC / (r0.x + r0.y + r0.z + r0.w);
                float v1 = FINC / (r1.x + r1.y + r1.z + r1.w);
                __hip_atomic_store(&vq[bid*8 + tid], pack2(v0, v1, (unsigned)(it + 1)),
                                   __ATOMIC_RELAXED, __HIP_MEMORY_SCOPE_AGENT);
            }
        }
        if (it == NITER) break;

        // ---- stage v (scaled f16) into xs ----
        {
            ull a, b;
            poll_gen2(&vq[2*tid], &vq[2*tid + 1], (unsigned)(it + 1), a, b);
            float f0 = fminf(unpAs(a), 60000.f), f1 = fminf(unpBs(a), 60000.f);
            float f2 = fminf(unpAs(b), 60000.f), f3 = fminf(unpBs(b), 60000.f);
            uint32 w0 = pkh(f0, f1), w1 = pkh(f2, f3);
            *(ull*)xsw2 = ((ull)w1 << 32) | w0;
        }
        __syncthreads();                                    // S3: xs ready

        // ---- half B: u_r = FINC / Σ K[r,:]·(v·S), rows 4g..4g+3 slice s from kq registers ----
        {
            u32x4 x0 = *(const u32x4*)((const char*)xs + xoff0);
            u32x4 x1 = *(const u32x4*)((const char*)xs + xoff1);
            float p[4];
            #pragma unroll
            for (int j = 0; j < 4; ++j) p[j] = dpp_sum(dot16h(kq[j][0], kq[j][1], x0, x1));
            if (lane == 63) {
                red[4*g+0][s] = p[0]; red[4*g+1][s] = p[1];
                red[4*g+2][s] = p[2]; red[4*g+3][s] = p[3];
            }
            __syncthreads();                                // S4: red complete
            if (tid < 8) {
                float4 r0 = *(float4*)&red[2*tid][0];
                float4 r1 = *(float4*)&red[2*tid + 1][0];
                float u0 = FINC / (r0.x + r0.y + r0.z + r0.w);
                float u1 = FINC / (r1.x + r1.y + r1.z + r1.w);
                us[2*tid] = u0; us[2*tid + 1] = u1;
                __hip_atomic_store(&uq[bid*8 + tid], pack2(u0, u1, (unsigned)(it + 1)),
                                   __ATOMIC_RELAXED, __HIP_MEMORY_SCOPE_AGENT);
            }
        }
        // next iter's S1 orders red/us reuse — no extra sync needed
    }

    // ---- final: P = u[:,None] * K * v[None,:] in place over d_out (fp32 K, fp32 u/v: exact) ----
    {
        ull a, b;
        poll_gen2(&vq[2*tid], &vq[2*tid + 1], (unsigned)(NITER + 1), a, b);
        *(float4*)((char*)xs + 16*sgrp(tid)) = make_float4(unpA(a), unpB(a), unpA(b), unpB(b));
        __syncthreads();

        const float ur = us[w];                      // wave w scales row base+w (u gen 200, exact fp32)
        float4* kp = (float4*)(K + (size_t)(base + w) * NPTS);
        #pragma unroll
        for (int t = 0; t < 16; ++t) {
            int G = t*64 + lane;
            float4 kk = kp[G];
            float4 vv = *(const float4*)((const char*)xs + 16*sgrp(G));
            kk.x *= ur * vv.x; kk.y *= ur * vv.y; kk.z *= ur * vv.z; kk.w *= ur * vv.w;
            kp[G] = kk;
        }
    }
}

// ---------------- non-cooperative fallback kernels (fp32 K only; insurance path) ----------------
__global__ void __launch_bounds__(1024) stepA_kernel(const float* __restrict__ K,
                                                     const float* __restrict__ u, float* __restrict__ v,
                                                     int first)
{
    const int w = threadIdx.x >> 6, lane = threadIdx.x & 63;
    const int r = blockIdx.x * 16 + w;
    float acc = f32_col_dot(K, u, r, lane, first);
    acc = wave_red_sum(acc);
    if (lane == 0) v[r] = INVN / acc;
}

__global__ void __launch_bounds__(1024) stepB_kernel(const float* __restrict__ K,
                                                     const float* __restrict__ v, float* __restrict__ u)
{
    const int w = threadIdx.x >> 6, lane = threadIdx.x & 63;
    const int r = blockIdx.x * 16 + w;
    float acc = f32_row_dot(K + (size_t)r * NPTS, v, lane);
    acc = wave_red_sum(acc);
    if (lane == 0) u[r] = INVN / acc;
}

__global__ void __launch_bounds__(1024) final_kernel(float* __restrict__ K,
                                                     const float* __restrict__ u,
                                                     const float* __restrict__ v)
{
    const int w = threadIdx.x >> 6, lane = threadIdx.x & 63;
    const int r = blockIdx.x * 16 + w;
    const float ur = u[r];
    float4* kp = (float4*)(K + (size_t)r * NPTS);
    const float4* vp = (const float4*)v;
    #pragma unroll
    for (int s = 0; s < 16; ++s) {
        int e4 = s * 64 + lane;
        float4 kk = kp[e4], vv = vp[e4];
        kk.x *= ur * vv.x; kk.y *= ur * vv.y; kk.z *= ur * vv.z; kk.w *= ur * vv.w;
        kp[e4] = kk;
    }
}

extern "C" void kernel_launch(void* const* d_in, const int* in_sizes, int n_in,
                              void* d_out, int out_size, void* d_ws, size_t ws_size,
                              hipStream_t stream)
{
    (void)in_sizes; (void)n_in; (void)out_size;
    const float* sn2d  = (const float*)d_in[0];
    const float* sn3d  = (const float*)d_in[1];
    const float* pix2d = (const float*)d_in[2];
    const float* pts3d = (const float*)d_in[3];
    const float* intr  = (const float*)d_in[4];
    const float* W1i = (const float*)d_in[5];  const float* b1i = (const float*)d_in[6];
    const float* W2i = (const float*)d_in[7];  const float* b2i = (const float*)d_in[8];
    const float* W3i = (const float*)d_in[9];  const float* b3i = (const float*)d_in[10];
    const float* W1p = (const float*)d_in[11]; const float* b1p = (const float*)d_in[12];
    const float* W2p = (const float*)d_in[13]; const float* b2p = (const float*)d_in[14];
    const float* W3p = (const float*)d_in[15]; const float* b3p = (const float*)d_in[16];

    float* ws  = (float*)d_ws;
    float* f2d = ws;                       // 4096*128 fp32
    float* f3d = f2d + NPTS*FD;            // 4096*128 fp32
    float* x2  = f3d + NPTS*FD;            // 4096
    float* y2  = x2 + NPTS;                // 4096
    float* uf  = y2 + NPTS;                // 4096 (fallback path only)
    float* vf  = uf + NPTS;                // 4096 (fallback path only)
    ull*   uq  = (ull*)(vf + NPTS);        // 2048 packed (16 KB)
    ull*   vq  = uq + NPTS/2;              // 2048 packed (16 KB)
    unsigned short* KbT = (unsigned short*)(vq + NPTS/2);  // f16, 33.55 MB
    unsigned short* Kb  = KbT + (size_t)NPTS*NPTS;         // f16, 33.55 MB
    float* K   = (float*)d_out;            // fp32 K, scaled in place to P at the end

    const size_t base_bytes = (size_t)(2*NPTS*FD + 4*NPTS) * 4 + (size_t)2*NPTS*4 + (size_t)NPTS*8;
    const size_t f16_bytes  = (size_t)NPTS * NPTS * 2;
    const size_t need_full  = base_bytes + 2*f16_bytes;
    int coop_ok = (ws_size >= need_full) ? 1 : 0;
    int wantT = (ws_size >= base_bytes + f16_bytes)   ? 1 : 0;
    int wantB = (ws_size >= base_bytes + 2*f16_bytes) ? 1 : 0;

    feat_kernel<<<dim3(NPTS, 2), 128, 0, stream>>>(sn2d, sn3d, pix2d, pts3d, intr,
        W1i, b1i, W2i, b2i, W3i, b3i, W1p, b1p, W2p, b2p, W3p, b3p,
        f2d, f3d, x2, y2);

    cost_kernel<<<dim3(64, 64), 256, 0, stream>>>(f2d, f3d, x2, y2, K, Kb, KbT,
                                                  coop_ok ? uq : (ull*)0,
                                                  wantB, wantT);

    hipError_t err = hipErrorUnknown;
    if (coop_ok) {
        void* args[] = { (void*)&K, (void*)&Kb, (void*)&KbT, (void*)&uq, (void*)&vq };
        err = hipLaunchCooperativeKernel((const void*)sinkhorn_kernel,
                                         dim3(NBLK), dim3(1024), args, SMEM_BYTES, stream);
    }
    if (err != hipSuccess) {
        // non-cooperative fallback: fp32 K, one launch per half-step
        stepA_kernel<<<256, 1024, 0, stream>>>(K, uf, vf, 1);
        for (int i = 0; i < NITER; ++i) {
            stepB_kernel<<<256, 1024, 0, stream>>>(K, vf, uf);
            stepA_kernel<<<256, 1024, 0, stream>>>(K, uf, vf, 0);
        }
        final_kernel<<<256, 1024, 0, stream>>>(K, uf, vf);
    }
}

// Round 14
// 1441.296 us; speedup vs baseline: 2.7393x; 1.0009x over previous
//
#include <hip/hip_runtime.h>
#include <math.h>

#define NPTS 4096
#define FD   128
#define NITER 200
#define INVN (1.0f / 4096.0f)
#define NBLK 256
#define XSCALE 1024.0f
#define FINC 0.25f                        // (XSCALE / 4096): v = FINC / scaled_sum
#define SMEM_BYTES (NPTS * 4)             // 16 KB: f16 xs uses first 8 KB; final fp32 phase uses all

typedef unsigned int uint32;
typedef unsigned long long ull;
typedef unsigned int u32x4 __attribute__((ext_vector_type(4)));
typedef __fp16 h2v __attribute__((ext_vector_type(2)));   // clang's native half2 (matches amdgcn builtins)

__device__ __forceinline__ float sigmoidf_(float x) { return 1.0f / (1.0f + expf(-x)); }

// pack two fp32 -> 2xf16 (RTZ) in one u32
__device__ __forceinline__ uint32 pkh(float a, float b) {
    h2v h = __builtin_amdgcn_cvt_pkrtz(a, b);
    return __builtin_bit_cast(uint32, h);
}

// fp32 16B-granule swizzle (final phase only)
__device__ __forceinline__ int sgrp(int G) { return G ^ ((G >> 3) & 7); }

// ---- gen-stamped packed pair: floats a,b (low 4 mantissa bits dropped) + 8-bit gen ----
__device__ __forceinline__ ull pack2(float a, float b, unsigned gen) {
    return ((ull)(__float_as_uint(a) >> 4) << 36)
         | ((ull)(__float_as_uint(b) >> 4) << 8)
         | (ull)(gen & 0xFFu);
}
__device__ __forceinline__ float unpA(ull x) { return __uint_as_float(((uint32)(x >> 36)) << 4); }
__device__ __forceinline__ float unpB(ull x) { return __uint_as_float(((uint32)(x >> 8))  << 4); }
// scaled variants: multiply by 1024 via exponent add (values are positive normals)
__device__ __forceinline__ float unpAs(ull x) { return __uint_as_float((((uint32)(x >> 36)) << 4) + (10u << 23)); }
__device__ __forceinline__ float unpBs(ull x) { return __uint_as_float((((uint32)(x >> 8))  << 4) + (10u << 23)); }

// poll two stamped words in parallel (both loads in flight before waiting)
__device__ __forceinline__ void poll_gen2(const ull* p0, const ull* p1, unsigned expect,
                                          ull& a, ull& b) {
    a = __hip_atomic_load(p0, __ATOMIC_RELAXED, __HIP_MEMORY_SCOPE_AGENT);
    b = __hip_atomic_load(p1, __ATOMIC_RELAXED, __HIP_MEMORY_SCOPE_AGENT);
    int gd = 0;
    while (((unsigned)(a & 0xFFu) != expect) | ((unsigned)(b & 0xFFu) != expect)) {
        __builtin_amdgcn_s_sleep(1);
        if ((unsigned)(a & 0xFFu) != expect)
            a = __hip_atomic_load(p0, __ATOMIC_RELAXED, __HIP_MEMORY_SCOPE_AGENT);
        if ((unsigned)(b & 0xFFu) != expect)
            b = __hip_atomic_load(p1, __ATOMIC_RELAXED, __HIP_MEMORY_SCOPE_AGENT);
        if (++gd > (1 << 24)) break;     // hang insurance only
    }
}

// canonical GCN 64-lane DPP sum; result valid in lane 63
__device__ __forceinline__ float dpp_sum(float x) {
    asm volatile("v_add_f32 %0, %0, %0 row_shr:1 bound_ctrl:0\n\t"
                 "v_add_f32 %0, %0, %0 row_shr:2 bound_ctrl:0\n\t"
                 "v_add_f32 %0, %0, %0 row_shr:4 bound_ctrl:0\n\t"
                 "v_add_f32 %0, %0, %0 row_shr:8 bound_ctrl:0\n\t"
                 "v_add_f32 %0, %0, %0 row_bcast:15 row_mask:0xa bank_mask:0xf\n\t"
                 "v_add_f32 %0, %0, %0 row_bcast:31 row_mask:0xc bank_mask:0xf"
                 : "+v"(x));
    return x;
}

// dot of 16 f16 K elems (2 u32x4) with 16 f16 x elems (2 u32x4) via v_dot2_f32_f16
__device__ __forceinline__ float dot16h(u32x4 a, u32x4 b, u32x4 x0, u32x4 x1) {
    float acc = 0.0f;
    #pragma unroll
    for (int q = 0; q < 4; ++q)
        acc = __builtin_amdgcn_fdot2(__builtin_bit_cast(h2v, a[q]),
                                     __builtin_bit_cast(h2v, x0[q]), acc, false);
    #pragma unroll
    for (int q = 0; q < 4; ++q)
        acc = __builtin_amdgcn_fdot2(__builtin_bit_cast(h2v, b[q]),
                                     __builtin_bit_cast(h2v, x1[q]), acc, false);
    return acc;
}

// helpers for the non-cooperative fallback path (fp32 K only)
__device__ __forceinline__ float wave_red_sum(float a) {
    #pragma unroll
    for (int m = 32; m >= 1; m >>= 1) a += __shfl_xor(a, m, 64);
    return a;
}

__device__ __forceinline__ float f32_row_dot(const float* __restrict__ Krow,
                                             const float* __restrict__ x, int lane)
{
    const float4* kp = (const float4*)Krow;
    const float4* xp = (const float4*)x;
    float acc = 0.0f;
    #pragma unroll
    for (int s = 0; s < 16; ++s) {
        int i = s*64 + lane;
        float4 kk = kp[i], xx = xp[i];
        acc += kk.x*xx.x + kk.y*xx.y + kk.z*xx.z + kk.w*xx.w;
    }
    return acc;
}

__device__ __forceinline__ float f32_col_dot(const float* __restrict__ K,
                                             const float* __restrict__ u,
                                             int col, int lane, int first)
{
    float acc = 0.0f;
    for (int i = lane; i < NPTS; i += 64)
        acc += K[(size_t)i*NPTS + col] * (first ? 1.0f : u[i]);
    return acc;
}

// ---------------- feature MLP kernel: one block (128 thr) per row, side = blockIdx.y ----------------
__global__ void feat_kernel(const float* __restrict__ sn2d, const float* __restrict__ sn3d,
                            const float* __restrict__ pix2d, const float* __restrict__ pts3d,
                            const float* __restrict__ intr,
                            const float* __restrict__ W1i, const float* __restrict__ b1i,
                            const float* __restrict__ W2i, const float* __restrict__ b2i,
                            const float* __restrict__ W3i, const float* __restrict__ b3i,
                            const float* __restrict__ W1p, const float* __restrict__ b1p,
                            const float* __restrict__ W2p, const float* __restrict__ b2p,
                            const float* __restrict__ W3p, const float* __restrict__ b3p,
                            float* __restrict__ f2d, float* __restrict__ f3d,
                            float* __restrict__ x2, float* __restrict__ y2)
{
    const int row  = blockIdx.x;
    const int side = blockIdx.y;
    const int tid  = threadIdx.x;

    __shared__ float xin[6];
    __shared__ float h1s[64];
    __shared__ float h2s[128];
    __shared__ float red[2];

    const float* W1 = side ? W1p : W1i;  const float* B1 = side ? b1p : b1i;
    const float* W2 = side ? W2p : W2i;  const float* B2 = side ? b2p : b2i;
    const float* W3 = side ? W3p : W3i;  const float* B3 = side ? b3p : b3i;

    if (tid == 0) {
        if (side == 0) {
            float a0 = sn2d[row*3+0], a1 = sn2d[row*3+1], a2 = sn2d[row*3+2];
            float n = fmaxf(sqrtf(a0*a0 + a1*a1 + a2*a2), 1e-12f);
            xin[0] = a0/n; xin[1] = a1/n; xin[2] = a2/n;
            float m00 = intr[0], m01 = intr[1], m02 = intr[2];
            float m10 = intr[3], m11 = intr[4], m12 = intr[5];
            float m20 = intr[6], m21 = intr[7], m22 = intr[8];
            float det = m00*(m11*m22 - m12*m21) - m01*(m10*m22 - m12*m20) + m02*(m10*m21 - m11*m20);
            float id = 1.0f/det;
            float i00 = (m11*m22 - m12*m21)*id;
            float i01 = (m02*m21 - m01*m22)*id;
            float i02 = (m01*m12 - m02*m11)*id;
            float i10 = (m12*m20 - m10*m22)*id;
            float i11 = (m00*m22 - m02*m20)*id;
            float i12 = (m02*m10 - m00*m12)*id;
            float i20 = (m10*m21 - m11*m20)*id;
            float i21 = (m01*m20 - m00*m21)*id;
            float i22 = (m00*m11 - m01*m10)*id;
            float px = pix2d[row*2+0], py = pix2d[row*2+1];
            float e0 = i00*px + i01*py + i02;
            float e1 = i10*px + i11*py + i12;
            float e2 = i20*px + i21*py + i22;
            float nb = fmaxf(sqrtf(e0*e0 + e1*e1 + e2*e2), 1e-12f);
            xin[3] = e1/nb; xin[4] = e0/nb; xin[5] = e2/nb;
        } else {
            float a0 = sn3d[row*3+0], a1 = sn3d[row*3+1], a2 = sn3d[row*3+2];
            float n = fmaxf(sqrtf(a0*a0 + a1*a1 + a2*a2), 1e-12f);
            xin[0] = a0/n; xin[1] = a1/n; xin[2] = a2/n;
            float p0 = pts3d[row*3+0], p1 = pts3d[row*3+1], p2 = pts3d[row*3+2];
            float pn = fmaxf(sqrtf(p0*p0 + p1*p1 + p2*p2), 1e-12f);
            xin[3] = p0/pn; xin[4] = p1/pn; xin[5] = p2/pn;
        }
    }
    __syncthreads();
    if (tid < 64) {
        float a = B1[tid];
        #pragma unroll
        for (int k = 0; k < 6; ++k) a += xin[k] * W1[tid*6 + k];
        h1s[tid] = sigmoidf_(a);
    }
    __syncthreads();
    {
        float a = B2[tid];
        #pragma unroll 8
        for (int k = 0; k < 64; ++k) a += h1s[k] * W2[tid*64 + k];
        h2s[tid] = sigmoidf_(a);
    }
    __syncthreads();
    float a = B3[tid];
    #pragma unroll 8
    for (int k = 0; k < 128; ++k) a += h2s[k] * W3[tid*128 + k];
    float o = sigmoidf_(a);

    float ss = o*o;
    #pragma unroll
    for (int m = 32; m >= 1; m >>= 1) ss += __shfl_xor(ss, m, 64);
    if ((tid & 63) == 0) red[tid >> 6] = ss;
    __syncthreads();
    float tot = red[0] + red[1];
    float n = fmaxf(sqrtf(tot), 1e-12f);
    float f = o / n;
    (side ? f3d : f2d)[row*FD + tid] = f;

    float ss2 = f*f;
    #pragma unroll
    for (int m = 32; m >= 1; m >>= 1) ss2 += __shfl_xor(ss2, m, 64);
    __syncthreads();
    if ((tid & 63) == 0) red[tid >> 6] = ss2;
    __syncthreads();
    if (tid == 0) (side ? y2 : x2)[row] = red[0] + red[1];
}

// ---------------- cost kernel: 64x64 tile; writes fp32 K, f16 Kb (row), f16 KbT (col), clears stamps ----------------
__global__ void __launch_bounds__(256) cost_kernel(const float* __restrict__ f2d, const float* __restrict__ f3d,
                                                   const float* __restrict__ x2, const float* __restrict__ y2,
                                                   float* __restrict__ K,
                                                   unsigned short* __restrict__ Kb,
                                                   unsigned short* __restrict__ KbT,
                                                   ull* __restrict__ quv,
                                                   int wantB, int wantT)
{
    __shared__ float As[128][64];
    __shared__ float Bs[128][64];
    const int tid = threadIdx.x;
    const int i0 = blockIdx.y * 64;
    const int j0 = blockIdx.x * 64;

    // clear gen-stamped u/v arrays (4096 ulls) so stale stamps never match (incl. 0xAA poison)
    if (quv && blockIdx.y == 0) {
        int idx = blockIdx.x * 256 + tid;
        if (idx < 4096) quv[idx] = 0ull;
    }

    {
        int r0 = tid >> 5;
        int c  = (tid & 31) * 4;
        for (int rr = r0; rr < 64; rr += 8) {
            float4 av = *(const float4*)(f2d + (size_t)(i0+rr)*FD + c);
            As[c+0][rr] = av.x; As[c+1][rr] = av.y; As[c+2][rr] = av.z; As[c+3][rr] = av.w;
            float4 bv = *(const float4*)(f3d + (size_t)(j0+rr)*FD + c);
            Bs[c+0][rr] = bv.x; Bs[c+1][rr] = bv.y; Bs[c+2][rr] = bv.z; Bs[c+3][rr] = bv.w;
        }
    }
    __syncthreads();

    const int tx = tid & 15;
    const int ty = tid >> 4;
    float acc[4][4] = {};
    for (int k = 0; k < 128; ++k) {
        float4 av = *(const float4*)&As[k][ty*4];
        float4 bv = *(const float4*)&Bs[k][tx*4];
        float aa[4] = {av.x, av.y, av.z, av.w};
        float bb[4] = {bv.x, bv.y, bv.z, bv.w};
        #pragma unroll
        for (int i = 0; i < 4; ++i)
            #pragma unroll
            for (int j = 0; j < 4; ++j)
                acc[i][j] += aa[i] * bb[j];
    }

    float kv[4][4];
    #pragma unroll
    for (int i = 0; i < 4; ++i) {
        int gi = i0 + ty*4 + i;
        float xv = x2[gi];
        #pragma unroll
        for (int j = 0; j < 4; ++j) {
            int gj = j0 + tx*4 + j;
            float d2 = xv + y2[gj] - 2.0f * acc[i][j];
            d2 = fmaxf(d2, 1e-12f);
            kv[i][j] = expf(-sqrtf(d2) * 10.0f);
        }
    }

    #pragma unroll
    for (int i = 0; i < 4; ++i) {
        int gi = i0 + ty*4 + i;
        *(float4*)(K + (size_t)gi*NPTS + j0 + tx*4) = make_float4(kv[i][0], kv[i][1], kv[i][2], kv[i][3]);
        if (wantB) {
            uint2 p; p.x = pkh(kv[i][0], kv[i][1]); p.y = pkh(kv[i][2], kv[i][3]);
            *(uint2*)(Kb + (size_t)gi*NPTS + j0 + tx*4) = p;
        }
    }
    if (wantT) {
        #pragma unroll
        for (int j = 0; j < 4; ++j) {
            int gj = j0 + tx*4 + j;
            uint2 p; p.x = pkh(kv[0][j], kv[1][j]); p.y = pkh(kv[2][j], kv[3][j]);
            *(uint2*)(KbT + (size_t)gj*NPTS + i0 + ty*4) = p;
        }
    }
}

// ---------------- persistent Sinkhorn v10: split-K registers + linear xs (conflict-free) ----------------
// wave w = (g = w>>2 row/col group, s = w&3 slice). Lane l owns elements
// [s*1024+8l, +8) and [s*1024+512+8l, +8) — non-adjacent halves so xs reads are lane-consecutive.
__global__ void __launch_bounds__(1024)
__attribute__((amdgpu_waves_per_eu(4, 4)))
sinkhorn_kernel(float* __restrict__ K,
                const unsigned short* __restrict__ Kb,
                const unsigned short* __restrict__ KbT,
                ull* __restrict__ uq,
                ull* __restrict__ vq)
{
    extern __shared__ char smem[];
    float* xs = (float*)smem;            // iteration: first 8 KB = f16-packed x (LINEAR); final: 16 KB fp32
    __shared__ float red[16][4];
    __shared__ float us[16];

    const int tid  = threadIdx.x;
    const int w    = tid >> 6;
    const int lane = tid & 63;
    const int g    = w >> 2;
    const int s    = w & 3;
    const int bid  = blockIdx.x;
    const int base = bid * 16;

    // f16 staging slot: thread t owns elems 4t..4t+3 -> bytes 8t..8t+7 (linear)
    char* xsw2 = (char*)xs + 8*tid;
    // f16 read offsets: lane's halves at granules s*128+lane and s*128+64+lane (lane-consecutive)
    const int xoff0 = 16*(s*128 + lane);
    const int xoff1 = xoff0 + 1024;

    // one-time: my 4 rows x split-slice of BOTH Kb and KbT into registers (64 VGPRs)
    u32x4 kq[4][2], kt[4][2];
    #pragma unroll
    for (int j = 0; j < 4; ++j) {
        const size_t off = (size_t)(base + 4*g + j) * NPTS + s*1024 + lane*8;
        kq[j][0] = *(const u32x4*)(Kb  + off);
        kq[j][1] = *(const u32x4*)(Kb  + off + 512);
        kt[j][0] = *(const u32x4*)(KbT + off);
        kt[j][1] = *(const u32x4*)(KbT + off + 512);
    }

    for (int it = 0; it <= NITER; ++it) {
        // pin the data tile in VGPRs (loop-carried dep -> no remat; round-9 proven)
        #pragma unroll
        for (int j = 0; j < 4; ++j)
            asm volatile("" : "+v"(kq[j][0]), "+v"(kq[j][1]), "+v"(kt[j][0]), "+v"(kt[j][1]));

        // ---- stage u (or ones), scaled by 1024, as packed f16 into linear xs ----
        if (it == 0) {
            uint32 o1 = pkh(XSCALE, XSCALE);
            *(ull*)xsw2 = ((ull)o1 << 32) | o1;
        } else {
            ull a, b;
            poll_gen2(&uq[2*tid], &uq[2*tid + 1], (unsigned)it, a, b);
            float f0 = fminf(unpAs(a), 60000.f), f1 = fminf(unpBs(a), 60000.f);
            float f2 = fminf(unpAs(b), 60000.f), f3 = fminf(unpBs(b), 60000.f);
            uint32 w0 = pkh(f0, f1), w1 = pkh(f2, f3);
            *(ull*)xsw2 = ((ull)w1 << 32) | w0;
        }
        __syncthreads();                                    // S1: xs ready (also orders red reuse)

        // ---- half A: v_c = FINC / Σ K[:,c]·(u·S), cols 4g..4g+3 slice s from kt registers ----
        {
            u32x4 x0 = *(const u32x4*)((const char*)xs + xoff0);
            u32x4 x1 = *(const u32x4*)((const char*)xs + xoff1);
            float p[4];
            #pragma unroll
            for (int j = 0; j < 4; ++j) p[j] = dpp_sum(dot16h(kt[j][0], kt[j][1], x0, x1));
            if (lane == 63) {
                red[4*g+0][s] = p[0]; red[4*g+1][s] = p[1];
                red[4*g+2][s] = p[2]; red[4*g+3][s] = p[3];
            }
            __syncthreads();                                // S2: red complete
            if (tid < 8) {
                float4 r0 = *(float4*)&red[2*tid][0];
                float4 r1 = *(float4*)&red[2*tid + 1][0];
                float v0 = FINC / (r0.x + r0.y + r0.z + r0.w);
                float v1 = FINC / (r1.x + r1.y + r1.z + r1.w);
                __hip_atomic_store(&vq[bid*8 + tid], pack2(v0, v1, (unsigned)(it + 1)),
                                   __ATOMIC_RELAXED, __HIP_MEMORY_SCOPE_AGENT);
            }
        }
        if (it == NITER) break;

        // ---- stage v (scaled f16) into linear xs ----
        {
            ull a, b;
            poll_gen2(&vq[2*tid], &vq[2*tid + 1], (unsigned)(it + 1), a, b);
            float f0 = fminf(unpAs(a), 60000.f), f1 = fminf(unpBs(a), 60000.f);
            float f2 = fminf(unpAs(b), 60000.f), f3 = fminf(unpBs(b), 60000.f);
            uint32 w0 = pkh(f0, f1), w1 = pkh(f2, f3);
            *(ull*)xsw2 = ((ull)w1 << 32) | w0;
        }
        __syncthreads();                                    // S3: xs ready

        // ---- half B: u_r = FINC / Σ K[r,:]·(v·S), rows 4g..4g+3 slice s from kq registers ----
        {
            u32x4 x0 = *(const u32x4*)((const char*)xs + xoff0);
            u32x4 x1 = *(const u32x4*)((const char*)xs + xoff1);
            float p[4];
            #pragma unroll
            for (int j = 0; j < 4; ++j) p[j] = dpp_sum(dot16h(kq[j][0], kq[j][1], x0, x1));
            if (lane == 63) {
                red[4*g+0][s] = p[0]; red[4*g+1][s] = p[1];
                red[4*g+2][s] = p[2]; red[4*g+3][s] = p[3];
            }
            __syncthreads();                                // S4: red complete
            if (tid < 8) {
                float4 r0 = *(float4*)&red[2*tid][0];
                float4 r1 = *(float4*)&red[2*tid + 1][0];
                float u0 = FINC / (r0.x + r0.y + r0.z + r0.w);
                float u1 = FINC / (r1.x + r1.y + r1.z + r1.w);
                us[2*tid] = u0; us[2*tid + 1] = u1;
                __hip_atomic_store(&uq[bid*8 + tid], pack2(u0, u1, (unsigned)(it + 1)),
                                   __ATOMIC_RELAXED, __HIP_MEMORY_SCOPE_AGENT);
            }
        }
        // next iter's S1 orders red/us reuse — no extra sync needed
    }

    // ---- final: P = u[:,None] * K * v[None,:] in place over d_out (fp32 K, fp32 u/v: exact) ----
    {
        ull a, b;
        poll_gen2(&vq[2*tid], &vq[2*tid + 1], (unsigned)(NITER + 1), a, b);
        *(float4*)((char*)xs + 16*sgrp(tid)) = make_float4(unpA(a), unpB(a), unpA(b), unpB(b));
        __syncthreads();

        const float ur = us[w];                      // wave w scales row base+w (u gen 200, exact fp32)
        float4* kp = (float4*)(K + (size_t)(base + w) * NPTS);
        #pragma unroll
        for (int t = 0; t < 16; ++t) {
            int G = t*64 + lane;
            float4 kk = kp[G];
            float4 vv = *(const float4*)((const char*)xs + 16*sgrp(G));
            kk.x *= ur * vv.x; kk.y *= ur * vv.y; kk.z *= ur * vv.z; kk.w *= ur * vv.w;
            kp[G] = kk;
        }
    }
}

// ---------------- non-cooperative fallback kernels (fp32 K only; insurance path) ----------------
__global__ void __launch_bounds__(1024) stepA_kernel(const float* __restrict__ K,
                                                     const float* __restrict__ u, float* __restrict__ v,
                                                     int first)
{
    const int w = threadIdx.x >> 6, lane = threadIdx.x & 63;
    const int r = blockIdx.x * 16 + w;
    float acc = f32_col_dot(K, u, r, lane, first);
    acc = wave_red_sum(acc);
    if (lane == 0) v[r] = INVN / acc;
}

__global__ void __launch_bounds__(1024) stepB_kernel(const float* __restrict__ K,
                                                     const float* __restrict__ v, float* __restrict__ u)
{
    const int w = threadIdx.x >> 6, lane = threadIdx.x & 63;
    const int r = blockIdx.x * 16 + w;
    float acc = f32_row_dot(K + (size_t)r * NPTS, v, lane);
    acc = wave_red_sum(acc);
    if (lane == 0) u[r] = INVN / acc;
}

__global__ void __launch_bounds__(1024) final_kernel(float* __restrict__ K,
                                                     const float* __restrict__ u,
                                                     const float* __restrict__ v)
{
    const int w = threadIdx.x >> 6, lane = threadIdx.x & 63;
    const int r = blockIdx.x * 16 + w;
    const float ur = u[r];
    float4* kp = (float4*)(K + (size_t)r * NPTS);
    const float4* vp = (const float4*)v;
    #pragma unroll
    for (int s = 0; s < 16; ++s) {
        int e4 = s * 64 + lane;
        float4 kk = kp[e4], vv = vp[e4];
        kk.x *= ur * vv.x; kk.y *= ur * vv.y; kk.z *= ur * vv.z; kk.w *= ur * vv.w;
        kp[e4] = kk;
    }
}

extern "C" void kernel_launch(void* const* d_in, const int* in_sizes, int n_in,
                              void* d_out, int out_size, void* d_ws, size_t ws_size,
                              hipStream_t stream)
{
    (void)in_sizes; (void)n_in; (void)out_size;
    const float* sn2d  = (const float*)d_in[0];
    const float* sn3d  = (const float*)d_in[1];
    const float* pix2d = (const float*)d_in[2];
    const float* pts3d = (const float*)d_in[3];
    const float* intr  = (const float*)d_in[4];
    const float* W1i = (const float*)d_in[5];  const float* b1i = (const float*)d_in[6];
    const float* W2i = (const float*)d_in[7];  const float* b2i = (const float*)d_in[8];
    const float* W3i = (const float*)d_in[9];  const float* b3i = (const float*)d_in[10];
    const float* W1p = (const float*)d_in[11]; const float* b1p = (const float*)d_in[12];
    const float* W2p = (const float*)d_in[13]; const float* b2p = (const float*)d_in[14];
    const float* W3p = (const float*)d_in[15]; const float* b3p = (const float*)d_in[16];

    float* ws  = (float*)d_ws;
    float* f2d = ws;                       // 4096*128 fp32
    float* f3d = f2d + NPTS*FD;            // 4096*128 fp32
    float* x2  = f3d + NPTS*FD;            // 4096
    float* y2  = x2 + NPTS;                // 4096
    float* uf  = y2 + NPTS;                // 4096 (fallback path only)
    float* vf  = uf + NPTS;                // 4096 (fallback path only)
    ull*   uq  = (ull*)(vf + NPTS);        // 2048 packed (16 KB)
    ull*   vq  = uq + NPTS/2;              // 2048 packed (16 KB)
    unsigned short* KbT = (unsigned short*)(vq + NPTS/2);  // f16, 33.55 MB
    unsigned short* Kb  = KbT + (size_t)NPTS*NPTS;         // f16, 33.55 MB
    float* K   = (float*)d_out;            // fp32 K, scaled in place to P at the end

    const size_t base_bytes = (size_t)(2*NPTS*FD + 4*NPTS) * 4 + (size_t)2*NPTS*4 + (size_t)NPTS*8;
    const size_t f16_bytes  = (size_t)NPTS * NPTS * 2;
    const size_t need_full  = base_bytes + 2*f16_bytes;
    int coop_ok = (ws_size >= need_full) ? 1 : 0;
    int wantT = (ws_size >= base_bytes + f16_bytes)   ? 1 : 0;
    int wantB = (ws_size >= base_bytes + 2*f16_bytes) ? 1 : 0;

    feat_kernel<<<dim3(NPTS, 2), 128, 0, stream>>>(sn2d, sn3d, pix2d, pts3d, intr,
        W1i, b1i, W2i, b2i, W3i, b3i, W1p, b1p, W2p, b2p, W3p, b3p,
        f2d, f3d, x2, y2);

    cost_kernel<<<dim3(64, 64), 256, 0, stream>>>(f2d, f3d, x2, y2, K, Kb, KbT,
                                                  coop_ok ? uq : (ull*)0,
                                                  wantB, wantT);

    hipError_t err = hipErrorUnknown;
    if (coop_ok) {
        void* args[] = { (void*)&K, (void*)&Kb, (void*)&KbT, (void*)&uq, (void*)&vq };
        err = hipLaunchCooperativeKernel((const void*)sinkhorn_kernel,
                                         dim3(NBLK), dim3(1024), args, SMEM_BYTES, stream);
    }
    if (err != hipSuccess) {
        // non-cooperative fallback: fp32 K, one launch per half-step
        stepA_kernel<<<256, 1024, 0, stream>>>(K, uf, vf, 1);
        for (int i = 0; i < NITER; ++i) {
            stepB_kernel<<<256, 1024, 0, stream>>>(K, vf, uf);
            stepA_kernel<<<256, 1024, 0, stream>>>(K, uf, vf, 0);
        }
        final_kernel<<<256, 1024, 0, stream>>>(K, uf, vf);
    }
}